// Round 1
// baseline (1346.664 us; speedup 1.0000x reference)
//
#include <hip/hip_runtime.h>
#include <hip/hip_bf16.h>
#include <math.h>

#define H_ 16
#define DK_ 128
#define DV_ 128
#define D_ 2048
#define T_ 256
#define B_ 2
#define BT_ 512

__device__ __forceinline__ float sigmoidf_(float x){ return 1.f/(1.f+expf(-x)); }
__device__ __forceinline__ float siluf_(float x){ return x/(1.f+expf(-x)); }

// ---------------- generic fp32 tiled GEMM: C[M,N] = A[M,K] @ W[K,N] ----------------
__global__ __launch_bounds__(256) void gemm64(const float* __restrict__ A,
    const float* __restrict__ W, float* __restrict__ C, int M, int N, int K)
{
    __shared__ float As[16][68];
    __shared__ float Ws[16][68];
    const int tx = threadIdx.x & 15, ty = threadIdx.x >> 4;
    const int m0 = blockIdx.y * 64, n0 = blockIdx.x * 64;
    float acc[4][4] = {};
    for (int k0 = 0; k0 < K; k0 += 16) {
        #pragma unroll
        for (int i = 0; i < 4; ++i) {
            int idx = threadIdx.x + i * 256;
            int m  = idx >> 4, kk = idx & 15;
            As[kk][m] = A[(size_t)(m0 + m) * K + (k0 + kk)];
            int kk2 = idx >> 6, n = idx & 63;
            Ws[kk2][n] = W[(size_t)(k0 + kk2) * N + (n0 + n)];
        }
        __syncthreads();
        #pragma unroll
        for (int kk = 0; kk < 16; ++kk) {
            const float4 a4 = *(const float4*)(&As[kk][ty * 4]);
            const float4 b4 = *(const float4*)(&Ws[kk][tx * 4]);
            const float av[4] = {a4.x, a4.y, a4.z, a4.w};
            const float bv[4] = {b4.x, b4.y, b4.z, b4.w};
            #pragma unroll
            for (int i = 0; i < 4; ++i)
                #pragma unroll
                for (int j = 0; j < 4; ++j)
                    acc[i][j] = fmaf(av[i], bv[j], acc[i][j]);
        }
        __syncthreads();
    }
    #pragma unroll
    for (int i = 0; i < 4; ++i)
        #pragma unroll
        for (int j = 0; j < 4; ++j)
            C[(size_t)(m0 + ty * 4 + i) * N + (n0 + tx * 4 + j)] = acc[i][j];
}

// ---------------- causal depthwise conv (K=4) + SiLU ----------------
__global__ void conv_silu(const float* __restrict__ in, const float* __restrict__ w,
                          float* __restrict__ out)
{
    int c  = blockIdx.x * 256 + threadIdx.x;   // 0..2047
    int bt = blockIdx.y;                        // b*T + t
    int b  = bt / T_, t = bt % T_;
    float acc = 0.f;
    #pragma unroll
    for (int j = 0; j < 4; ++j) {
        int tt = t - 3 + j;
        if (tt >= 0) acc = fmaf(w[c * 4 + j], in[((size_t)(b * T_ + tt)) * D_ + c], acc);
    }
    out[(size_t)bt * D_ + c] = siluf_(acc);
}

// ---------------- g_chan = -exp(A_log)[:,None] * softplus(dt_bias).reshape(H,DK) ----
__global__ void gchan_k(const float* __restrict__ A_log, const float* __restrict__ dt_bias,
                        float* __restrict__ gchan)
{
    int i = blockIdx.x * 256 + threadIdx.x;    // 0..2047
    int h = i >> 7;
    float x = dt_bias[i];
    float sp = (x > 20.f) ? x : log1pf(expf(x));
    gchan[i] = -expf(A_log[h]) * sp;
}

// ---------------- entropy of softmax over 64 bins, normalized ----------------
__global__ void entropy_k(const float* __restrict__ logits, float* __restrict__ ent)
{
    int r = blockIdx.x;            // b*T+t, 512 rows
    int l = threadIdx.x;           // 0..63 (one full wave)
    float x = logits[r * 64 + l];
    float m = x;
    #pragma unroll
    for (int o = 32; o > 0; o >>= 1) m = fmaxf(m, __shfl_xor(m, o));
    float e = expf(x - m);
    float s = e;
    #pragma unroll
    for (int o = 32; o > 0; o >>= 1) s += __shfl_xor(s, o);
    float lp = (x - m) - logf(s);
    float c = -expf(lp) * lp;
    #pragma unroll
    for (int o = 32; o > 0; o >>= 1) c += __shfl_xor(c, o);
    if (l == 0) ent[r] = c / logf(64.f);
}

// ---------------- per-(b,t,h) features + tiny MLP -> scalars ----------------
__global__ __launch_bounds__(128) void feats_k(
    const float* __restrict__ kc, const float* __restrict__ vc,
    const float* __restrict__ proxy, const float* __restrict__ ent,
    const float* __restrict__ he,
    const float* __restrict__ w1, const float* __restrict__ b1,
    const float* __restrict__ w2, const float* __restrict__ b2,
    const float* __restrict__ bbw, const float* __restrict__ bbb,
    const float* __restrict__ bdw, const float* __restrict__ bdb,
    const float* __restrict__ lamw, const float* __restrict__ lamb,
    const float* __restrict__ abw, const float* __restrict__ abb,
    const float* __restrict__ adw, const float* __restrict__ adb,
    float* __restrict__ bf, float* __restrict__ bs, float* __restrict__ lm,
    float* __restrict__ af, float* __restrict__ as2, float* __restrict__ kn)
{
    int blk = blockIdx.x;          // (b*T+t)*H + h
    int h = blk & 15, bt = blk >> 4;
    int b = bt / T_, t = bt % T_;
    int v = threadIdx.x;           // 0..127
    __shared__ float kv[128];
    __shared__ float part[2][5];
    __shared__ float tot5[5];
    __shared__ float feats8[8];
    __shared__ float hf1[32];
    __shared__ float hf[32];

    size_t base = (size_t)bt * D_ + h * 128;
    float kval = kc[base + v];
    float vval = vc[base + v];
    kv[v] = kval;
    __syncthreads();
    float vhat = 0.f;
    #pragma unroll 4
    for (int k = 0; k < 128; ++k) vhat = fmaf(kv[k], proxy[k * 128 + v], vhat);

    float e = vval - vhat;
    float sums[5] = {kval * kval, vval * vval, vhat * vhat, vval * vhat, e * e};
    #pragma unroll
    for (int i = 0; i < 5; ++i) {
        float s = sums[i];
        #pragma unroll
        for (int o = 32; o > 0; o >>= 1) s += __shfl_xor(s, o);
        if ((threadIdx.x & 63) == 0) part[threadIdx.x >> 6][i] = s;
    }
    __syncthreads();
    if (threadIdx.x < 5) tot5[threadIdx.x] = part[0][threadIdx.x] + part[1][threadIdx.x];
    __syncthreads();
    if (threadIdx.x == 0) {
        float k2 = tot5[0], v2 = tot5[1], vh2 = tot5[2], vvh = tot5[3], e2 = tot5[4];
        float knorm = sqrtf(k2);
        float err_n = sqrtf(e2);
        float v_n = sqrtf(v2);
        float vh_n = sqrtf(vh2);
        feats8[0] = ent[bt];
        feats8[1] = err_n / (v_n + 1e-6f);
        feats8[2] = vvh / (v_n * vh_n + 1e-6f);
        feats8[3] = log1pf(err_n);
        feats8[4] = he[h * 4 + 0];
        feats8[5] = he[h * 4 + 1];
        feats8[6] = he[h * 4 + 2];
        feats8[7] = he[h * 4 + 3];
        kn[((size_t)(b * H_ + h)) * T_ + t] = knorm;
    }
    __syncthreads();
    if (threadIdx.x < 32) {
        float a = b1[threadIdx.x];
        #pragma unroll
        for (int j = 0; j < 8; ++j) a = fmaf(feats8[j], w1[j * 32 + threadIdx.x], a);
        hf1[threadIdx.x] = siluf_(a);
    }
    __syncthreads();
    if (threadIdx.x < 32) {
        float a = b2[threadIdx.x];
        #pragma unroll
        for (int j = 0; j < 32; ++j) a = fmaf(hf1[j], w2[j * 32 + threadIdx.x], a);
        hf[threadIdx.x] = siluf_(a);
    }
    __syncthreads();
    if (threadIdx.x == 0) {
        float bb = bbb[0], bd = bdb[0], lv = lamb[0], ab = abb[0], ad = adb[0];
        #pragma unroll
        for (int j = 0; j < 32; ++j) {
            float hj = hf[j];
            bb = fmaf(hj, bbw[j], bb);
            bd = fmaf(hj, bdw[j], bd);
            lv = fmaf(hj, lamw[j], lv);
            ab = fmaf(hj, abw[j], ab);
            ad = fmaf(hj, adw[j], ad);
        }
        size_t o = ((size_t)(b * H_ + h)) * T_ + t;
        bf[o]  = sigmoidf_(bb + bd);
        bs[o]  = sigmoidf_(bb - bd);
        lm[o]  = sigmoidf_(lv);
        af[o]  = sigmoidf_(ab + ad);
        as2[o] = sigmoidf_(ab - ad);
    }
}

// ---------------- sequential delta rule scan: one block per (rule,b,h) ----------------
__global__ __launch_bounds__(256) void delta_k(
    const float* __restrict__ qc, const float* __restrict__ kc, const float* __restrict__ vc,
    const float* __restrict__ kn, const float* __restrict__ beta_f, const float* __restrict__ beta_s,
    const float* __restrict__ amp_f, const float* __restrict__ amp_s,
    const float* __restrict__ gchan,
    float* __restrict__ o_fast, float* __restrict__ o_slow)
{
    int blk = blockIdx.x;              // rule*32 + b*16 + h
    int rule = blk >> 5, bh = blk & 31, b = bh >> 4, h = bh & 15;
    const float* beta = rule ? beta_s : beta_f;
    const float* amp  = rule ? amp_s  : amp_f;
    float* oout = rule ? o_slow : o_fast;
    int tid = threadIdx.x, vcol = tid & 127, kh = tid >> 7;

    __shared__ float kg[128], dec[128], kb[128], qv[128], vv[128];
    __shared__ float red[256], red2[256];

    float S[64];
    #pragma unroll
    for (int i = 0; i < 64; ++i) S[i] = 0.f;

    size_t cbase = (size_t)b * T_ * D_ + h * 128;
    size_t sbase = (size_t)(b * H_ + h) * T_;

    for (int t = 0; t < T_; ++t) {
        if (tid < 128) {
            size_t rowb = cbase + (size_t)t * D_;
            float kval = kc[rowb + tid];
            float knv  = kn[sbase + t];
            float ku   = kval / (knv + 1e-6f);
            float a    = amp[sbase + t];
            float bt_  = beta[sbase + t];
            float d    = expf(gchan[h * 128 + tid] * a);
            dec[tid] = d;
            kg[tid]  = ku * d;
            kb[tid]  = ku * bt_;
            qv[tid]  = qc[rowb + tid] * 0.08838834764831845f;  // DK^-0.5
            vv[tid]  = vc[rowb + tid];
        }
        __syncthreads();                 // A
        const float* kgp = kg + kh * 64;
        float kp0 = 0, kp1 = 0, kp2 = 0, kp3 = 0;
        #pragma unroll
        for (int k = 0; k < 64; k += 4) {
            kp0 = fmaf(kgp[k],     S[k],     kp0);
            kp1 = fmaf(kgp[k + 1], S[k + 1], kp1);
            kp2 = fmaf(kgp[k + 2], S[k + 2], kp2);
            kp3 = fmaf(kgp[k + 3], S[k + 3], kp3);
        }
        red[tid] = (kp0 + kp1) + (kp2 + kp3);
        __syncthreads();                 // B
        float vpred = red[tid] + red[tid ^ 128];
        float dv = vv[vcol] - vpred;
        const float* decp = dec + kh * 64;
        const float* kbp  = kb + kh * 64;
        const float* qp   = qv + kh * 64;
        float o0 = 0, o1 = 0, o2 = 0, o3 = 0;
        #pragma unroll
        for (int k = 0; k < 64; k += 4) {
            S[k]     = fmaf(decp[k],     S[k],     kbp[k]     * dv); o0 = fmaf(qp[k],     S[k],     o0);
            S[k + 1] = fmaf(decp[k + 1], S[k + 1], kbp[k + 1] * dv); o1 = fmaf(qp[k + 1], S[k + 1], o1);
            S[k + 2] = fmaf(decp[k + 2], S[k + 2], kbp[k + 2] * dv); o2 = fmaf(qp[k + 2], S[k + 2], o2);
            S[k + 3] = fmaf(decp[k + 3], S[k + 3], kbp[k + 3] * dv); o3 = fmaf(qp[k + 3], S[k + 3], o3);
        }
        red2[tid] = (o0 + o1) + (o2 + o3);
        __syncthreads();                 // C
        if (kh == 0)
            oout[(size_t)(b * T_ + t) * D_ + h * 128 + vcol] = red2[tid] + red2[tid + 128];
        // next-iteration staging is safe: it only writes kg/dec/kb/qv/vv after barrier C,
        // and red/red2 are next written only after the next A/B barriers.
    }
}

// ---------------- combine fast/slow + RMSNorm + sigmoid gate ----------------
__global__ __launch_bounds__(128) void combine_k(
    const float* __restrict__ of, const float* __restrict__ os,
    const float* __restrict__ lm, const float* __restrict__ graw,
    const float* __restrict__ g2b, const float* __restrict__ onw,
    float* __restrict__ oc)
{
    int blk = blockIdx.x;          // (b*T+t)*H + h
    int h = blk & 15, bt = blk >> 4;
    int b = bt / T_, t = bt % T_;
    int v = threadIdx.x;
    size_t idx = (size_t)bt * D_ + h * 128 + v;
    float l = lm[((size_t)(b * H_ + h)) * T_ + t];
    float o = l * of[idx] + (1.f - l) * os[idx];
    float s = o * o;
    #pragma unroll
    for (int off = 32; off > 0; off >>= 1) s += __shfl_xor(s, off);
    __shared__ float ws2[2];
    if ((threadIdx.x & 63) == 0) ws2[threadIdx.x >> 6] = s;
    __syncthreads();
    float tot = ws2[0] + ws2[1];
    float rms = sqrtf(tot / 128.f + 1e-5f);
    float g = graw[idx] + g2b[h * 128 + v];
    oc[idx] = o / rms * onw[v] * sigmoidf_(g);
}

extern "C" void kernel_launch(void* const* d_in, const int* in_sizes, int n_in,
                              void* d_out, int out_size, void* d_ws, size_t ws_size,
                              hipStream_t stream)
{
    const float* x        = (const float*)d_in[0];
    const float* wq       = (const float*)d_in[1];
    const float* wk       = (const float*)d_in[2];
    const float* wv       = (const float*)d_in[3];
    const float* conv_q_w = (const float*)d_in[4];
    const float* conv_k_w = (const float*)d_in[5];
    const float* conv_v_w = (const float*)d_in[6];
    const float* A_log    = (const float*)d_in[7];
    const float* dt_bias  = (const float*)d_in[8];
    const float* proxy_w  = (const float*)d_in[9];
    const float* unc_w    = (const float*)d_in[10];
    const float* he       = (const float*)d_in[11];
    const float* mlp_w1   = (const float*)d_in[12];
    const float* mlp_b1   = (const float*)d_in[13];
    const float* mlp_w2   = (const float*)d_in[14];
    const float* mlp_b2   = (const float*)d_in[15];
    const float* bb_w     = (const float*)d_in[16];
    const float* bb_b     = (const float*)d_in[17];
    const float* bd_w     = (const float*)d_in[18];
    const float* bd_b     = (const float*)d_in[19];
    const float* lam_w    = (const float*)d_in[20];
    const float* lam_b    = (const float*)d_in[21];
    const float* ab_w     = (const float*)d_in[22];
    const float* ab_b     = (const float*)d_in[23];
    const float* ad_w     = (const float*)d_in[24];
    const float* ad_b     = (const float*)d_in[25];
    const float* g1_w     = (const float*)d_in[26];
    const float* g2_w     = (const float*)d_in[27];
    const float* g2_b     = (const float*)d_in[28];
    const float* onorm_w  = (const float*)d_in[29];
    const float* wo       = (const float*)d_in[30];
    float* out = (float*)d_out;

    float* ws = (float*)d_ws;
    const size_t SZ = (size_t)BT_ * D_;
    float* qraw   = ws;
    float* kraw   = qraw + SZ;
    float* vraw   = kraw + SZ;
    float* qc     = vraw + SZ;
    float* kc     = qc + SZ;
    float* vc     = kc + SZ;
    float* graw   = vc + SZ;
    float* logits = graw + SZ;              // BT*64
    float* gtmp   = logits + (size_t)BT_ * 64;   // BT*128
    float* ent    = gtmp + (size_t)BT_ * 128;    // BT
    float* sc     = ent + BT_;
    float* bf = sc, *bs = sc + 8192, *lm = sc + 16384, *af = sc + 24576,
         *as2 = sc + 32768, *kn = sc + 40960;
    float* gchan  = sc + 49152;             // 2048
    float* o_fast = qraw;                   // reuse (dead after conv)
    float* o_slow = kraw;
    float* oc     = vraw;

    dim3 blk256(256);

    // projections
    gemm64<<<dim3(32, 8), blk256, 0, stream>>>(x, wq, qraw, BT_, 2048, 2048);
    gemm64<<<dim3(32, 8), blk256, 0, stream>>>(x, wk, kraw, BT_, 2048, 2048);
    gemm64<<<dim3(32, 8), blk256, 0, stream>>>(x, wv, vraw, BT_, 2048, 2048);
    gemm64<<<dim3(1, 8),  blk256, 0, stream>>>(x, unc_w, logits, BT_, 64, 2048);
    gemm64<<<dim3(2, 8),  blk256, 0, stream>>>(x, g1_w, gtmp, BT_, 128, 2048);
    gemm64<<<dim3(32, 8), blk256, 0, stream>>>(gtmp, g2_w, graw, BT_, 2048, 128);

    // conv + silu
    conv_silu<<<dim3(8, BT_), blk256, 0, stream>>>(qraw, conv_q_w, qc);
    conv_silu<<<dim3(8, BT_), blk256, 0, stream>>>(kraw, conv_k_w, kc);
    conv_silu<<<dim3(8, BT_), blk256, 0, stream>>>(vraw, conv_v_w, vc);

    // small precomputations
    gchan_k<<<dim3(8), blk256, 0, stream>>>(A_log, dt_bias, gchan);
    entropy_k<<<dim3(BT_), dim3(64), 0, stream>>>(logits, ent);

    // per-(b,t,h) features + MLP
    feats_k<<<dim3(BT_ * H_), dim3(128), 0, stream>>>(
        kc, vc, proxy_w, ent, he, mlp_w1, mlp_b1, mlp_w2, mlp_b2,
        bb_w, bb_b, bd_w, bd_b, lam_w, lam_b, ab_w, ab_b, ad_w, ad_b,
        bf, bs, lm, af, as2, kn);

    // sequential delta rule (fast + slow)
    delta_k<<<dim3(64), blk256, 0, stream>>>(qc, kc, vc, kn, bf, bs, af, as2,
                                             gchan, o_fast, o_slow);

    // combine + rmsnorm + gate
    combine_k<<<dim3(BT_ * H_), dim3(128), 0, stream>>>(o_fast, o_slow, lm, graw,
                                                        g2_b, onorm_w, oc);

    // output projection
    gemm64<<<dim3(32, 8), blk256, 0, stream>>>(oc, wo, out, BT_, 2048, 2048);
}

// Round 2
// 554.457 us; speedup vs baseline: 2.4288x; 2.4288x over previous
//
#include <hip/hip_runtime.h>
#include <hip/hip_bf16.h>
#include <math.h>

#define H_ 16
#define DK_ 128
#define DV_ 128
#define D_ 2048
#define T_ 256
#define B_ 2
#define BT_ 512

typedef __attribute__((ext_vector_type(8))) short short8v;
typedef __attribute__((ext_vector_type(4))) float float4v;
typedef unsigned short ushort_t;

__device__ __forceinline__ float sigmoidf_(float x){ return 1.f/(1.f+expf(-x)); }
__device__ __forceinline__ float siluf_(float x){ return x/(1.f+expf(-x)); }
__device__ __forceinline__ ushort_t f2bf(float f){
    __hip_bfloat16 h = __float2bfloat16(f);
    return *reinterpret_cast<ushort_t*>(&h);
}

// ---------------- fp32 -> bf16 elementwise ----------------
__global__ void cvt_bf16(const float* __restrict__ in, ushort_t* __restrict__ out, int n){
    int i = (blockIdx.x * 256 + threadIdx.x) * 4;
    if (i >= n) return;
    float4 v = *(const float4*)&in[i];
    union { ushort_t s[4]; unsigned long long u; } p;
    p.s[0] = f2bf(v.x); p.s[1] = f2bf(v.y); p.s[2] = f2bf(v.z); p.s[3] = f2bf(v.w);
    *(unsigned long long*)&out[i] = p.u;
}

// ---------------- fp32 [K,N] -> bf16 [N,K] (transpose-convert) ----------------
__global__ __launch_bounds__(256) void transcvt(const float* __restrict__ in,
    ushort_t* __restrict__ out, int K, int N)
{
    __shared__ ushort_t tile[32][36];
    int k0 = blockIdx.y * 32, n0 = blockIdx.x * 32;
    int t = threadIdx.x;
    int r = t >> 3, c4 = (t & 7) * 4;
    float4 v = *(const float4*)&in[(size_t)(k0 + r) * N + n0 + c4];
    tile[c4 + 0][r] = f2bf(v.x);
    tile[c4 + 1][r] = f2bf(v.y);
    tile[c4 + 2][r] = f2bf(v.z);
    tile[c4 + 3][r] = f2bf(v.w);
    __syncthreads();
    union { ushort_t s[4]; unsigned long long u; } p;
    p.s[0] = tile[r][c4]; p.s[1] = tile[r][c4 + 1];
    p.s[2] = tile[r][c4 + 2]; p.s[3] = tile[r][c4 + 3];
    *(unsigned long long*)&out[(size_t)(n0 + r) * K + k0 + c4] = p.u;
}

// ---------------- bf16 MFMA GEMM: C[M,N] = A[M,K] @ Bt[N,K]^T, fp32 out ----------------
__global__ __launch_bounds__(256) void gemm_bt(
    const ushort_t* __restrict__ A, const ushort_t* __restrict__ Bt,
    float* __restrict__ C, int M, int N, int K)
{
    __shared__ ushort_t Asub[64][40];   // 40 = 32 + 8 pad -> 2-way (free) bank pattern
    __shared__ ushort_t Bsub[64][40];
    const int tid = threadIdx.x;
    const int m0 = blockIdx.y * 64, n0 = blockIdx.x * 64;
    const int wid = tid >> 6, lane = tid & 63;
    const int wr = (wid >> 1) * 32, wc = (wid & 1) * 32;
    const int srow = tid >> 2, sko = (tid & 3) * 8;
    const int lr = lane & 15, lk = (lane >> 4) * 8;

    float4v acc[2][2];
    #pragma unroll
    for (int i = 0; i < 2; ++i)
        #pragma unroll
        for (int j = 0; j < 2; ++j) acc[i][j] = (float4v){0.f, 0.f, 0.f, 0.f};

    const size_t arow = (size_t)(m0 + srow) * K;
    const size_t brow = (size_t)(n0 + srow) * K;
    for (int k0 = 0; k0 < K; k0 += 32) {
        *(float4*)&Asub[srow][sko] = *(const float4*)&A[arow + k0 + sko];
        *(float4*)&Bsub[srow][sko] = *(const float4*)&Bt[brow + k0 + sko];
        __syncthreads();
        short8v af[2], bfr[2];
        af[0]  = *(const short8v*)&Asub[wr + lr][lk];
        af[1]  = *(const short8v*)&Asub[wr + 16 + lr][lk];
        bfr[0] = *(const short8v*)&Bsub[wc + lr][lk];
        bfr[1] = *(const short8v*)&Bsub[wc + 16 + lr][lk];
        #pragma unroll
        for (int mi = 0; mi < 2; ++mi)
            #pragma unroll
            for (int ni = 0; ni < 2; ++ni)
                acc[mi][ni] = __builtin_amdgcn_mfma_f32_16x16x32_bf16(
                    af[mi], bfr[ni], acc[mi][ni], 0, 0, 0);
        __syncthreads();
    }
    const int lq = (lane >> 4) * 4;
    #pragma unroll
    for (int mi = 0; mi < 2; ++mi)
        #pragma unroll
        for (int ni = 0; ni < 2; ++ni)
            #pragma unroll
            for (int j = 0; j < 4; ++j)
                C[(size_t)(m0 + wr + mi * 16 + lq + j) * N + (n0 + wc + ni * 16 + lr)]
                    = acc[mi][ni][j];
}

// ---------------- causal depthwise conv (K=4) + SiLU (+scale) ----------------
__global__ void conv_silu(const float* __restrict__ in, const float* __restrict__ w,
                          float* __restrict__ out, float scale)
{
    int c  = blockIdx.x * 256 + threadIdx.x;   // 0..2047
    int bt = blockIdx.y;                        // b*T + t
    int b  = bt / T_, t = bt % T_;
    float acc = 0.f;
    #pragma unroll
    for (int j = 0; j < 4; ++j) {
        int tt = t - 3 + j;
        if (tt >= 0) acc = fmaf(w[c * 4 + j], in[((size_t)(b * T_ + tt)) * D_ + c], acc);
    }
    out[(size_t)bt * D_ + c] = siluf_(acc) * scale;
}

// ---------------- g_chan ----------------
__global__ void gchan_k(const float* __restrict__ A_log, const float* __restrict__ dt_bias,
                        float* __restrict__ gchan)
{
    int i = blockIdx.x * 256 + threadIdx.x;
    int h = i >> 7;
    float x = dt_bias[i];
    float sp = (x > 20.f) ? x : log1pf(expf(x));
    gchan[i] = -expf(A_log[h]) * sp;
}

// ---------------- entropy of softmax over 64 bins, normalized ----------------
__global__ void entropy_k(const float* __restrict__ logits, float* __restrict__ ent)
{
    int r = blockIdx.x;
    int l = threadIdx.x;           // 0..63
    float x = logits[r * 64 + l];
    float m = x;
    #pragma unroll
    for (int o = 32; o > 0; o >>= 1) m = fmaxf(m, __shfl_xor(m, o));
    float e = expf(x - m);
    float s = e;
    #pragma unroll
    for (int o = 32; o > 0; o >>= 1) s += __shfl_xor(s, o);
    float lp = (x - m) - logf(s);
    float c = -expf(lp) * lp;
    #pragma unroll
    for (int o = 32; o > 0; o >>= 1) c += __shfl_xor(c, o);
    if (l == 0) ent[r] = c / logf(64.f);
}

// ---------------- per-(b,t,h) features + tiny MLP -> scalars ----------------
__global__ __launch_bounds__(128) void feats_k(
    const float* __restrict__ kc, const float* __restrict__ vc,
    const float* __restrict__ proxy, const float* __restrict__ ent,
    const float* __restrict__ he,
    const float* __restrict__ w1, const float* __restrict__ b1,
    const float* __restrict__ w2, const float* __restrict__ b2,
    const float* __restrict__ bbw, const float* __restrict__ bbb,
    const float* __restrict__ bdw, const float* __restrict__ bdb,
    const float* __restrict__ lamw, const float* __restrict__ lamb,
    const float* __restrict__ abw, const float* __restrict__ abb,
    const float* __restrict__ adw, const float* __restrict__ adb,
    float* __restrict__ bf, float* __restrict__ bs, float* __restrict__ lm,
    float* __restrict__ af, float* __restrict__ as2, float* __restrict__ kn)
{
    int blk = blockIdx.x;          // (b*T+t)*H + h
    int h = blk & 15, bt = blk >> 4;
    int b = bt / T_, t = bt % T_;
    int v = threadIdx.x;           // 0..127
    __shared__ float kv[128];
    __shared__ float part[2][5];
    __shared__ float tot5[5];
    __shared__ float feats8[8];
    __shared__ float hf1[32];
    __shared__ float hf[32];

    size_t base = (size_t)bt * D_ + h * 128;
    float kval = kc[base + v];
    float vval = vc[base + v];
    kv[v] = kval;
    __syncthreads();
    float vhat = 0.f;
    #pragma unroll 4
    for (int k = 0; k < 128; ++k) vhat = fmaf(kv[k], proxy[k * 128 + v], vhat);

    float e = vval - vhat;
    float sums[5] = {kval * kval, vval * vval, vhat * vhat, vval * vhat, e * e};
    #pragma unroll
    for (int i = 0; i < 5; ++i) {
        float s = sums[i];
        #pragma unroll
        for (int o = 32; o > 0; o >>= 1) s += __shfl_xor(s, o);
        if ((threadIdx.x & 63) == 0) part[threadIdx.x >> 6][i] = s;
    }
    __syncthreads();
    if (threadIdx.x < 5) tot5[threadIdx.x] = part[0][threadIdx.x] + part[1][threadIdx.x];
    __syncthreads();
    if (threadIdx.x == 0) {
        float k2 = tot5[0], v2 = tot5[1], vh2 = tot5[2], vvh = tot5[3], e2 = tot5[4];
        float knorm = sqrtf(k2);
        float err_n = sqrtf(e2);
        float v_n = sqrtf(v2);
        float vh_n = sqrtf(vh2);
        feats8[0] = ent[bt];
        feats8[1] = err_n / (v_n + 1e-6f);
        feats8[2] = vvh / (v_n * vh_n + 1e-6f);
        feats8[3] = log1pf(err_n);
        feats8[4] = he[h * 4 + 0];
        feats8[5] = he[h * 4 + 1];
        feats8[6] = he[h * 4 + 2];
        feats8[7] = he[h * 4 + 3];
        kn[((size_t)(b * H_ + h)) * T_ + t] = knorm;
    }
    __syncthreads();
    if (threadIdx.x < 32) {
        float a = b1[threadIdx.x];
        #pragma unroll
        for (int j = 0; j < 8; ++j) a = fmaf(feats8[j], w1[j * 32 + threadIdx.x], a);
        hf1[threadIdx.x] = siluf_(a);
    }
    __syncthreads();
    if (threadIdx.x < 32) {
        float a = b2[threadIdx.x];
        #pragma unroll
        for (int j = 0; j < 32; ++j) a = fmaf(hf1[j], w2[j * 32 + threadIdx.x], a);
        hf[threadIdx.x] = siluf_(a);
    }
    __syncthreads();
    if (threadIdx.x == 0) {
        float bb = bbb[0], bd = bdb[0], lv = lamb[0], ab = abb[0], ad = adb[0];
        #pragma unroll
        for (int j = 0; j < 32; ++j) {
            float hj = hf[j];
            bb = fmaf(hj, bbw[j], bb);
            bd = fmaf(hj, bdw[j], bd);
            lv = fmaf(hj, lamw[j], lv);
            ab = fmaf(hj, abw[j], ab);
            ad = fmaf(hj, adw[j], ad);
        }
        size_t o = ((size_t)(b * H_ + h)) * T_ + t;
        bf[o]  = sigmoidf_(bb + bd);
        bs[o]  = sigmoidf_(bb - bd);
        lm[o]  = sigmoidf_(lv);
        af[o]  = sigmoidf_(ab + ad);
        as2[o] = sigmoidf_(ab - ad);
    }
}

// ---------------- delta-rule scan, register-tiled, v-split x2 ----------------
// block = (((rule*2+b)*16+h)*2+vh); 256 threads; thread owns S[8k][4v] in regs.
__global__ __launch_bounds__(256) void delta_tile(
    const float* __restrict__ qc, const float* __restrict__ kc, const float* __restrict__ vc,
    const float* __restrict__ kn, const float* __restrict__ beta_f, const float* __restrict__ beta_s,
    const float* __restrict__ amp_f, const float* __restrict__ amp_s,
    const float* __restrict__ gchan,
    float* __restrict__ o_fast, float* __restrict__ o_slow)
{
    const int blk = blockIdx.x;
    const int vh = blk & 1;
    const int h = (blk >> 1) & 15;
    const int b = (blk >> 5) & 1;
    const int rule = blk >> 6;
    const float* beta = rule ? beta_s : beta_f;
    const float* amp  = rule ? amp_s  : amp_f;
    float* oout = rule ? o_slow : o_fast;
    const int tid = threadIdx.x;
    const int kg8 = (tid >> 4) * 8;     // k-row base (0..120)
    const int vg4 = (tid & 15) * 4;     // local v-col base (0..60)

    __shared__ float kg[128], dec[128], kb[128], qv[128];
    __shared__ float dvs[64];
    __shared__ float red[16][68];       // pad 68 -> reduce reads conflict-free

    float S[8][4];
    #pragma unroll
    for (int j = 0; j < 8; ++j)
        #pragma unroll
        for (int i = 0; i < 4; ++i) S[j][i] = 0.f;

    const size_t cbase = (size_t)b * T_ * D_ + h * 128;
    const size_t sbase = (size_t)(b * H_ + h) * T_;

    float pk = 0.f, pq = 0.f, pv = 0.f, pkn = 0.f, pamp = 0.f, pbeta = 0.f, gch = 0.f;
    if (tid < 128) {
        gch = gchan[h * 128 + tid];
        pk = kc[cbase + tid];
        pq = qc[cbase + tid];
        pkn = kn[sbase]; pamp = amp[sbase]; pbeta = beta[sbase];
    }
    if (tid < 64) pv = vc[cbase + vh * 64 + tid];

    for (int t = 0; t < T_; ++t) {
        float vval = pv;
        if (tid < 128) {
            float ku = pk / (pkn + 1e-6f);
            float d = expf(gch * pamp);
            dec[tid] = d;
            kg[tid] = ku * d;
            kb[tid] = ku * pbeta;
            qv[tid] = pq;                 // q pre-scaled by DK^-0.5 in conv
        }
        __syncthreads();                  // A: staged vectors visible
        if (t + 1 < T_) {                 // prefetch next step into regs
            const size_t rowb = cbase + (size_t)(t + 1) * D_;
            if (tid < 128) {
                pk = kc[rowb + tid];
                pq = qc[rowb + tid];
                pkn = kn[sbase + t + 1];
                pamp = amp[sbase + t + 1];
                pbeta = beta[sbase + t + 1];
            }
            if (tid < 64) pv = vc[rowb + vh * 64 + tid];
        }
        // phase 2: vpred partials over this thread's 8 k-rows
        float kgr[8];
        *(float4*)&kgr[0] = *(const float4*)&kg[kg8];
        *(float4*)&kgr[4] = *(const float4*)&kg[kg8 + 4];
        float pp0 = 0, pp1 = 0, pp2 = 0, pp3 = 0;
        #pragma unroll
        for (int j = 0; j < 8; ++j) {
            pp0 = fmaf(kgr[j], S[j][0], pp0);
            pp1 = fmaf(kgr[j], S[j][1], pp1);
            pp2 = fmaf(kgr[j], S[j][2], pp2);
            pp3 = fmaf(kgr[j], S[j][3], pp3);
        }
        { float4 w; w.x = pp0; w.y = pp1; w.z = pp2; w.w = pp3;
          *(float4*)&red[tid >> 4][vg4] = w; }
        __syncthreads();                  // B
        if (tid < 64) {
            float s = 0.f;
            #pragma unroll
            for (int g = 0; g < 16; ++g) s += red[g][tid];
            dvs[tid] = vval - s;
        }
        __syncthreads();                  // C
        // phase 4: S update + output partials
        float dvr[4]; *(float4*)dvr = *(const float4*)&dvs[vg4];
        float dcr[8], kbr[8], qvr[8];
        *(float4*)&dcr[0] = *(const float4*)&dec[kg8];
        *(float4*)&dcr[4] = *(const float4*)&dec[kg8 + 4];
        *(float4*)&kbr[0] = *(const float4*)&kb[kg8];
        *(float4*)&kbr[4] = *(const float4*)&kb[kg8 + 4];
        *(float4*)&qvr[0] = *(const float4*)&qv[kg8];
        *(float4*)&qvr[4] = *(const float4*)&qv[kg8 + 4];
        float op0 = 0, op1 = 0, op2 = 0, op3 = 0;
        #pragma unroll
        for (int j = 0; j < 8; ++j) {
            float dj = dcr[j], bj = kbr[j], qj = qvr[j];
            S[j][0] = fmaf(dj, S[j][0], bj * dvr[0]); op0 = fmaf(qj, S[j][0], op0);
            S[j][1] = fmaf(dj, S[j][1], bj * dvr[1]); op1 = fmaf(qj, S[j][1], op1);
            S[j][2] = fmaf(dj, S[j][2], bj * dvr[2]); op2 = fmaf(qj, S[j][2], op2);
            S[j][3] = fmaf(dj, S[j][3], bj * dvr[3]); op3 = fmaf(qj, S[j][3], op3);
        }
        { float4 w; w.x = op0; w.y = op1; w.z = op2; w.w = op3;
          *(float4*)&red[tid >> 4][vg4] = w; }
        __syncthreads();                  // D
        if (tid < 64) {
            float s = 0.f;
            #pragma unroll
            for (int g = 0; g < 16; ++g) s += red[g][tid];
            oout[(size_t)(b * T_ + t) * D_ + h * 128 + vh * 64 + tid] = s;
        }
    }
}

// ---------------- combine fast/slow + RMSNorm + sigmoid gate -> bf16 ----------------
__global__ __launch_bounds__(128) void combine_k(
    const float* __restrict__ of, const float* __restrict__ os,
    const float* __restrict__ lm, const float* __restrict__ graw,
    const float* __restrict__ g2b, const float* __restrict__ onw,
    ushort_t* __restrict__ ocb)
{
    int blk = blockIdx.x;          // (b*T+t)*H + h
    int h = blk & 15, bt = blk >> 4;
    int b = bt / T_, t = bt % T_;
    int v = threadIdx.x;
    size_t idx = (size_t)bt * D_ + h * 128 + v;
    float l = lm[((size_t)(b * H_ + h)) * T_ + t];
    float o = l * of[idx] + (1.f - l) * os[idx];
    float s = o * o;
    #pragma unroll
    for (int off = 32; off > 0; off >>= 1) s += __shfl_xor(s, off);
    __shared__ float ws2[2];
    if ((threadIdx.x & 63) == 0) ws2[threadIdx.x >> 6] = s;
    __syncthreads();
    float tot = ws2[0] + ws2[1];
    float rms = sqrtf(tot / 128.f + 1e-5f);
    float g = graw[idx] + g2b[h * 128 + v];
    ocb[idx] = f2bf(o / rms * onw[v] * sigmoidf_(g));
}

extern "C" void kernel_launch(void* const* d_in, const int* in_sizes, int n_in,
                              void* d_out, int out_size, void* d_ws, size_t ws_size,
                              hipStream_t stream)
{
    const float* x        = (const float*)d_in[0];
    const float* wq       = (const float*)d_in[1];
    const float* wk       = (const float*)d_in[2];
    const float* wv       = (const float*)d_in[3];
    const float* conv_q_w = (const float*)d_in[4];
    const float* conv_k_w = (const float*)d_in[5];
    const float* conv_v_w = (const float*)d_in[6];
    const float* A_log    = (const float*)d_in[7];
    const float* dt_bias  = (const float*)d_in[8];
    const float* proxy_w  = (const float*)d_in[9];
    const float* unc_w    = (const float*)d_in[10];
    const float* he       = (const float*)d_in[11];
    const float* mlp_w1   = (const float*)d_in[12];
    const float* mlp_b1   = (const float*)d_in[13];
    const float* mlp_w2   = (const float*)d_in[14];
    const float* mlp_b2   = (const float*)d_in[15];
    const float* bb_w     = (const float*)d_in[16];
    const float* bb_b     = (const float*)d_in[17];
    const float* bd_w     = (const float*)d_in[18];
    const float* bd_b     = (const float*)d_in[19];
    const float* lam_w    = (const float*)d_in[20];
    const float* lam_b    = (const float*)d_in[21];
    const float* ab_w     = (const float*)d_in[22];
    const float* ab_b     = (const float*)d_in[23];
    const float* ad_w     = (const float*)d_in[24];
    const float* ad_b     = (const float*)d_in[25];
    const float* g1_w     = (const float*)d_in[26];
    const float* g2_w     = (const float*)d_in[27];
    const float* g2_b     = (const float*)d_in[28];
    const float* onorm_w  = (const float*)d_in[29];
    const float* wo       = (const float*)d_in[30];
    float* out = (float*)d_out;

    float* ws = (float*)d_ws;
    const size_t SZ = (size_t)BT_ * D_;          // 1,048,576
    float* qraw   = ws;
    float* kraw   = qraw + SZ;
    float* vraw   = kraw + SZ;
    float* qc     = vraw + SZ;
    float* kc     = qc + SZ;
    float* vc     = kc + SZ;
    float* graw   = vc + SZ;
    float* logits = graw + SZ;                   // 32768
    float* gtmp   = logits + 32768;              // 65536
    float* ent    = gtmp + 65536;                // 512
    float* bf     = ent + 512;
    float* bs     = bf + 8192;
    float* lm     = bs + 8192;
    float* af     = lm + 8192;
    float* as2    = af + 8192;
    float* kn     = as2 + 8192;
    float* gchan  = kn + 8192;                   // 2048
    float* fend   = gchan + 2048;
    ushort_t* xb    = (ushort_t*)fend;           // 1,048,576 bf16
    ushort_t* gtmpb = xb + SZ;                   // 65,536 bf16
    ushort_t* wT    = gtmpb + 65536;             // up to 4,194,304 bf16
    // total ws usage ~= 40.6 MB

    float* o_fast = qraw;                        // reuse (dead after conv)
    float* o_slow = kraw;
    ushort_t* ocb = (ushort_t*)vraw;

    dim3 blk256(256);
    const float QSCALE = 0.08838834764831845f;   // DK^-0.5

    // x -> bf16
    cvt_bf16<<<dim3(1024), blk256, 0, stream>>>(x, xb, (int)SZ);

    // projections (bf16 MFMA); weight transposed-converted into shared wT slot
    transcvt<<<dim3(64, 64), blk256, 0, stream>>>(wq, wT, 2048, 2048);
    gemm_bt<<<dim3(32, 8), blk256, 0, stream>>>(xb, wT, qraw, 512, 2048, 2048);
    transcvt<<<dim3(64, 64), blk256, 0, stream>>>(wk, wT, 2048, 2048);
    gemm_bt<<<dim3(32, 8), blk256, 0, stream>>>(xb, wT, kraw, 512, 2048, 2048);
    transcvt<<<dim3(64, 64), blk256, 0, stream>>>(wv, wT, 2048, 2048);
    gemm_bt<<<dim3(32, 8), blk256, 0, stream>>>(xb, wT, vraw, 512, 2048, 2048);
    transcvt<<<dim3(2, 64), blk256, 0, stream>>>(unc_w, wT, 2048, 64);
    gemm_bt<<<dim3(1, 8), blk256, 0, stream>>>(xb, wT, logits, 512, 64, 2048);
    transcvt<<<dim3(4, 64), blk256, 0, stream>>>(g1_w, wT, 2048, 128);
    gemm_bt<<<dim3(2, 8), blk256, 0, stream>>>(xb, wT, gtmp, 512, 128, 2048);
    cvt_bf16<<<dim3(64), blk256, 0, stream>>>(gtmp, gtmpb, 65536);
    transcvt<<<dim3(64, 4), blk256, 0, stream>>>(g2_w, wT, 128, 2048);
    gemm_bt<<<dim3(32, 8), blk256, 0, stream>>>(gtmpb, wT, graw, 512, 2048, 128);

    // conv + silu (q pre-scaled)
    conv_silu<<<dim3(8, BT_), blk256, 0, stream>>>(qraw, conv_q_w, qc, QSCALE);
    conv_silu<<<dim3(8, BT_), blk256, 0, stream>>>(kraw, conv_k_w, kc, 1.f);
    conv_silu<<<dim3(8, BT_), blk256, 0, stream>>>(vraw, conv_v_w, vc, 1.f);

    // small precomputations
    gchan_k<<<dim3(8), blk256, 0, stream>>>(A_log, dt_bias, gchan);
    entropy_k<<<dim3(BT_), dim3(64), 0, stream>>>(logits, ent);

    // per-(b,t,h) features + MLP
    feats_k<<<dim3(BT_ * H_), dim3(128), 0, stream>>>(
        kc, vc, proxy_w, ent, he, mlp_w1, mlp_b1, mlp_w2, mlp_b2,
        bb_w, bb_b, bd_w, bd_b, lam_w, lam_b, ab_w, ab_b, ad_w, ad_b,
        bf, bs, lm, af, as2, kn);

    // sequential delta rule (fast + slow), v-split x2 -> 128 blocks
    delta_tile<<<dim3(128), blk256, 0, stream>>>(qc, kc, vc, kn, bf, bs, af, as2,
                                                 gchan, o_fast, o_slow);

    // combine + rmsnorm + gate -> bf16
    combine_k<<<dim3(BT_ * H_), dim3(128), 0, stream>>>(o_fast, o_slow, lm, graw,
                                                        g2_b, onorm_w, ocb);

    // output projection
    transcvt<<<dim3(64, 64), blk256, 0, stream>>>(wo, wT, 2048, 2048);
    gemm_bt<<<dim3(32, 8), blk256, 0, stream>>>(ocb, wT, out, 512, 2048, 2048);
}

// Round 3
// 458.971 us; speedup vs baseline: 2.9341x; 1.2080x over previous
//
#include <hip/hip_runtime.h>
#include <hip/hip_bf16.h>
#include <math.h>

#define H_ 16
#define DK_ 128
#define DV_ 128
#define D_ 2048
#define T_ 256
#define B_ 2
#define BT_ 512

typedef __attribute__((ext_vector_type(8))) short short8v;
typedef __attribute__((ext_vector_type(4))) float float4v;
typedef unsigned short ushort_t;

__device__ __forceinline__ float sigmoidf_(float x){ return 1.f/(1.f+expf(-x)); }
__device__ __forceinline__ float siluf_(float x){ return x/(1.f+expf(-x)); }
__device__ __forceinline__ ushort_t f2bf(float f){
    __hip_bfloat16 h = __float2bfloat16(f);
    return *reinterpret_cast<ushort_t*>(&h);
}

// ---------------- fp32 -> bf16 elementwise ----------------
__global__ void cvt_bf16(const float* __restrict__ in, ushort_t* __restrict__ out, int n){
    int i = (blockIdx.x * 256 + threadIdx.x) * 4;
    if (i >= n) return;
    float4 v = *(const float4*)&in[i];
    union { ushort_t s[4]; unsigned long long u; } p;
    p.s[0] = f2bf(v.x); p.s[1] = f2bf(v.y); p.s[2] = f2bf(v.z); p.s[3] = f2bf(v.w);
    *(unsigned long long*)&out[i] = p.u;
}

// ---------------- fp32 [K,N] -> bf16 [N,K] (transpose-convert) ----------------
__global__ __launch_bounds__(256) void transcvt(const float* __restrict__ in,
    ushort_t* __restrict__ out, int K, int N)
{
    __shared__ ushort_t tile[32][36];
    int k0 = blockIdx.y * 32, n0 = blockIdx.x * 32;
    int t = threadIdx.x;
    int r = t >> 3, c4 = (t & 7) * 4;
    float4 v = *(const float4*)&in[(size_t)(k0 + r) * N + n0 + c4];
    tile[c4 + 0][r] = f2bf(v.x);
    tile[c4 + 1][r] = f2bf(v.y);
    tile[c4 + 2][r] = f2bf(v.z);
    tile[c4 + 3][r] = f2bf(v.w);
    __syncthreads();
    union { ushort_t s[4]; unsigned long long u; } p;
    p.s[0] = tile[r][c4]; p.s[1] = tile[r][c4 + 1];
    p.s[2] = tile[r][c4 + 2]; p.s[3] = tile[r][c4 + 3];
    *(unsigned long long*)&out[(size_t)(n0 + r) * K + k0 + c4] = p.u;
}

// ---------------- bf16 MFMA GEMM: C[M,N] = A[M,K] @ Bt[N,K]^T, fp32 out ----------------
__global__ __launch_bounds__(256) void gemm_bt(
    const ushort_t* __restrict__ A, const ushort_t* __restrict__ Bt,
    float* __restrict__ C, int M, int N, int K)
{
    __shared__ ushort_t Asub[64][40];   // 40 = 32 + 8 pad -> 2-way (free) bank pattern
    __shared__ ushort_t Bsub[64][40];
    const int tid = threadIdx.x;
    const int m0 = blockIdx.y * 64, n0 = blockIdx.x * 64;
    const int wid = tid >> 6, lane = tid & 63;
    const int wr = (wid >> 1) * 32, wc = (wid & 1) * 32;
    const int srow = tid >> 2, sko = (tid & 3) * 8;
    const int lr = lane & 15, lk = (lane >> 4) * 8;

    float4v acc[2][2];
    #pragma unroll
    for (int i = 0; i < 2; ++i)
        #pragma unroll
        for (int j = 0; j < 2; ++j) acc[i][j] = (float4v){0.f, 0.f, 0.f, 0.f};

    const size_t arow = (size_t)(m0 + srow) * K;
    const size_t brow = (size_t)(n0 + srow) * K;
    for (int k0 = 0; k0 < K; k0 += 32) {
        *(float4*)&Asub[srow][sko] = *(const float4*)&A[arow + k0 + sko];
        *(float4*)&Bsub[srow][sko] = *(const float4*)&Bt[brow + k0 + sko];
        __syncthreads();
        short8v af[2], bfr[2];
        af[0]  = *(const short8v*)&Asub[wr + lr][lk];
        af[1]  = *(const short8v*)&Asub[wr + 16 + lr][lk];
        bfr[0] = *(const short8v*)&Bsub[wc + lr][lk];
        bfr[1] = *(const short8v*)&Bsub[wc + 16 + lr][lk];
        #pragma unroll
        for (int mi = 0; mi < 2; ++mi)
            #pragma unroll
            for (int ni = 0; ni < 2; ++ni)
                acc[mi][ni] = __builtin_amdgcn_mfma_f32_16x16x32_bf16(
                    af[mi], bfr[ni], acc[mi][ni], 0, 0, 0);
        __syncthreads();
    }
    const int lq = (lane >> 4) * 4;
    #pragma unroll
    for (int mi = 0; mi < 2; ++mi)
        #pragma unroll
        for (int ni = 0; ni < 2; ++ni)
            #pragma unroll
            for (int j = 0; j < 4; ++j)
                C[(size_t)(m0 + wr + mi * 16 + lq + j) * N + (n0 + wc + ni * 16 + lr)]
                    = acc[mi][ni][j];
}

// ---------------- causal depthwise conv (K=4) + SiLU (+scale) ----------------
__global__ void conv_silu(const float* __restrict__ in, const float* __restrict__ w,
                          float* __restrict__ out, float scale)
{
    int c  = blockIdx.x * 256 + threadIdx.x;   // 0..2047
    int bt = blockIdx.y;                        // b*T + t
    int b  = bt / T_, t = bt % T_;
    float acc = 0.f;
    #pragma unroll
    for (int j = 0; j < 4; ++j) {
        int tt = t - 3 + j;
        if (tt >= 0) acc = fmaf(w[c * 4 + j], in[((size_t)(b * T_ + tt)) * D_ + c], acc);
    }
    out[(size_t)bt * D_ + c] = siluf_(acc) * scale;
}

// ---------------- g_chan (pre-scaled by log2(e) for exp2f in the scan) ----------------
__global__ void gchan_k(const float* __restrict__ A_log, const float* __restrict__ dt_bias,
                        float* __restrict__ gchan)
{
    int i = blockIdx.x * 256 + threadIdx.x;
    int h = i >> 7;
    float x = dt_bias[i];
    float sp = (x > 20.f) ? x : log1pf(expf(x));
    gchan[i] = -expf(A_log[h]) * sp * 1.44269504088896f;
}

// ---------------- entropy of softmax over 64 bins, normalized ----------------
__global__ void entropy_k(const float* __restrict__ logits, float* __restrict__ ent)
{
    int r = blockIdx.x;
    int l = threadIdx.x;           // 0..63
    float x = logits[r * 64 + l];
    float m = x;
    #pragma unroll
    for (int o = 32; o > 0; o >>= 1) m = fmaxf(m, __shfl_xor(m, o));
    float e = expf(x - m);
    float s = e;
    #pragma unroll
    for (int o = 32; o > 0; o >>= 1) s += __shfl_xor(s, o);
    float lp = (x - m) - logf(s);
    float c = -expf(lp) * lp;
    #pragma unroll
    for (int o = 32; o > 0; o >>= 1) c += __shfl_xor(c, o);
    if (l == 0) ent[r] = c / logf(64.f);
}

// ---------------- per-(b,t,h) features + tiny MLP -> scalars ----------------
__global__ __launch_bounds__(128) void feats_k(
    const float* __restrict__ kc, const float* __restrict__ vc,
    const float* __restrict__ proxy, const float* __restrict__ ent,
    const float* __restrict__ he,
    const float* __restrict__ w1, const float* __restrict__ b1,
    const float* __restrict__ w2, const float* __restrict__ b2,
    const float* __restrict__ bbw, const float* __restrict__ bbb,
    const float* __restrict__ bdw, const float* __restrict__ bdb,
    const float* __restrict__ lamw, const float* __restrict__ lamb,
    const float* __restrict__ abw, const float* __restrict__ abb,
    const float* __restrict__ adw, const float* __restrict__ adb,
    float* __restrict__ bf, float* __restrict__ bs, float* __restrict__ lm,
    float* __restrict__ af, float* __restrict__ as2, float* __restrict__ kn)
{
    int blk = blockIdx.x;          // (b*T+t)*H + h
    int h = blk & 15, bt = blk >> 4;
    int b = bt / T_, t = bt % T_;
    int v = threadIdx.x;           // 0..127
    __shared__ float kv[128];
    __shared__ float part[2][5];
    __shared__ float tot5[5];
    __shared__ float feats8[8];
    __shared__ float hf1[32];
    __shared__ float hf[32];

    size_t base = (size_t)bt * D_ + h * 128;
    float kval = kc[base + v];
    float vval = vc[base + v];
    kv[v] = kval;
    __syncthreads();
    float vhat = 0.f;
    #pragma unroll 4
    for (int k = 0; k < 128; ++k) vhat = fmaf(kv[k], proxy[k * 128 + v], vhat);

    float e = vval - vhat;
    float sums[5] = {kval * kval, vval * vval, vhat * vhat, vval * vhat, e * e};
    #pragma unroll
    for (int i = 0; i < 5; ++i) {
        float s = sums[i];
        #pragma unroll
        for (int o = 32; o > 0; o >>= 1) s += __shfl_xor(s, o);
        if ((threadIdx.x & 63) == 0) part[threadIdx.x >> 6][i] = s;
    }
    __syncthreads();
    if (threadIdx.x < 5) tot5[threadIdx.x] = part[0][threadIdx.x] + part[1][threadIdx.x];
    __syncthreads();
    if (threadIdx.x == 0) {
        float k2 = tot5[0], v2 = tot5[1], vh2 = tot5[2], vvh = tot5[3], e2 = tot5[4];
        float knorm = sqrtf(k2);
        float err_n = sqrtf(e2);
        float v_n = sqrtf(v2);
        float vh_n = sqrtf(vh2);
        feats8[0] = ent[bt];
        feats8[1] = err_n / (v_n + 1e-6f);
        feats8[2] = vvh / (v_n * vh_n + 1e-6f);
        feats8[3] = log1pf(err_n);
        feats8[4] = he[h * 4 + 0];
        feats8[5] = he[h * 4 + 1];
        feats8[6] = he[h * 4 + 2];
        feats8[7] = he[h * 4 + 3];
        kn[((size_t)(b * H_ + h)) * T_ + t] = knorm;
    }
    __syncthreads();
    if (threadIdx.x < 32) {
        float a = b1[threadIdx.x];
        #pragma unroll
        for (int j = 0; j < 8; ++j) a = fmaf(feats8[j], w1[j * 32 + threadIdx.x], a);
        hf1[threadIdx.x] = siluf_(a);
    }
    __syncthreads();
    if (threadIdx.x < 32) {
        float a = b2[threadIdx.x];
        #pragma unroll
        for (int j = 0; j < 32; ++j) a = fmaf(hf1[j], w2[j * 32 + threadIdx.x], a);
        hf[threadIdx.x] = siluf_(a);
    }
    __syncthreads();
    if (threadIdx.x == 0) {
        float bb = bbb[0], bd = bdb[0], lv = lamb[0], ab = abb[0], ad = adb[0];
        #pragma unroll
        for (int j = 0; j < 32; ++j) {
            float hj = hf[j];
            bb = fmaf(hj, bbw[j], bb);
            bd = fmaf(hj, bdw[j], bd);
            lv = fmaf(hj, lamw[j], lv);
            ab = fmaf(hj, abw[j], ab);
            ad = fmaf(hj, adw[j], ad);
        }
        size_t o = ((size_t)(b * H_ + h)) * T_ + t;
        bf[o]  = sigmoidf_(bb + bd);
        bs[o]  = sigmoidf_(bb - bd);
        lm[o]  = sigmoidf_(lv);
        af[o]  = sigmoidf_(ab + ad);
        as2[o] = sigmoidf_(ab - ad);
    }
}

// ---------------- delta-rule scan, pure-register, per-wave independent ----------------
// 2048 waves total: rule(2) x b(2) x h(16) x v-chunk(32). Wave = 16 k-lanes x 4 v-groups.
// Lane owns S[8k][1v] in registers. No LDS, no barriers; reductions via shfl_xor over
// 16-lane k-groups. Next-step globals prefetched into a second register struct.
struct DR { float k[8]; float q[8]; float v, kn, am, bt; };

__device__ __forceinline__ void dload(DR& r,
    const float* __restrict__ kc, const float* __restrict__ qc, const float* __restrict__ vc,
    const float* __restrict__ knp, const float* __restrict__ ampp, const float* __restrict__ betp,
    size_t kqbase, size_t vbase, size_t sbase, int t)
{
    const size_t row = (size_t)t * D_;
    float4 x0 = *(const float4*)&kc[kqbase + row];
    float4 x1 = *(const float4*)&kc[kqbase + row + 4];
    r.k[0] = x0.x; r.k[1] = x0.y; r.k[2] = x0.z; r.k[3] = x0.w;
    r.k[4] = x1.x; r.k[5] = x1.y; r.k[6] = x1.z; r.k[7] = x1.w;
    float4 y0 = *(const float4*)&qc[kqbase + row];
    float4 y1 = *(const float4*)&qc[kqbase + row + 4];
    r.q[0] = y0.x; r.q[1] = y0.y; r.q[2] = y0.z; r.q[3] = y0.w;
    r.q[4] = y1.x; r.q[5] = y1.y; r.q[6] = y1.z; r.q[7] = y1.w;
    r.v  = vc[vbase + row];
    r.kn = knp[sbase + t];
    r.am = ampp[sbase + t];
    r.bt = betp[sbase + t];
}

__global__ __launch_bounds__(256) void delta_wave(
    const float* __restrict__ qc, const float* __restrict__ kc, const float* __restrict__ vc,
    const float* __restrict__ knp, const float* __restrict__ beta_f, const float* __restrict__ beta_s,
    const float* __restrict__ amp_f, const float* __restrict__ amp_s,
    const float* __restrict__ gchan,
    float* __restrict__ o_fast, float* __restrict__ o_slow)
{
    const int w     = blockIdx.x * 4 + (threadIdx.x >> 6);
    const int lane  = threadIdx.x & 63;
    const int chunk = w & 31;
    const int h     = (w >> 5) & 15;
    const int b     = (w >> 9) & 1;
    const int rule  = w >> 10;
    const int kl    = lane & 15;
    const int vg    = lane >> 4;
    const int vcol  = chunk * 4 + vg;

    const float* __restrict__ betp = rule ? beta_s : beta_f;
    const float* __restrict__ ampp = rule ? amp_s  : amp_f;
    float* __restrict__ oout = rule ? o_slow : o_fast;

    const size_t kqbase = (size_t)b * T_ * D_ + h * 128 + kl * 8;
    const size_t vbase  = (size_t)b * T_ * D_ + h * 128 + vcol;
    const size_t sbase  = (size_t)(b * H_ + h) * T_;
    float* __restrict__ obase = oout + (size_t)b * T_ * D_ + h * 128 + vcol;

    float gch2[8];
    #pragma unroll
    for (int j = 0; j < 8; ++j) gch2[j] = gchan[h * 128 + kl * 8 + j];

    float S[8];
    #pragma unroll
    for (int j = 0; j < 8; ++j) S[j] = 0.f;

#define DSTEP(TT, CUR, NXT) do {                                                   \
    float rkn = 1.f / (CUR.kn + 1e-6f);                                            \
    float d_[8], kg_[8], kb_[8];                                                   \
    _Pragma("unroll")                                                              \
    for (int j = 0; j < 8; ++j) {                                                  \
        float ku = CUR.k[j] * rkn;                                                 \
        d_[j]  = exp2f(gch2[j] * CUR.am);                                          \
        kg_[j] = ku * d_[j];                                                       \
        kb_[j] = ku * CUR.bt;                                                      \
    }                                                                              \
    if ((TT) + 1 < T_)                                                             \
        dload(NXT, kc, qc, vc, knp, ampp, betp, kqbase, vbase, sbase, (TT) + 1);   \
    float vp = 0.f;                                                                \
    _Pragma("unroll")                                                              \
    for (int j = 0; j < 8; ++j) vp = fmaf(kg_[j], S[j], vp);                       \
    vp += __shfl_xor(vp, 1); vp += __shfl_xor(vp, 2);                              \
    vp += __shfl_xor(vp, 4); vp += __shfl_xor(vp, 8);                              \
    float dv = CUR.v - vp;                                                         \
    float o = 0.f;                                                                 \
    _Pragma("unroll")                                                              \
    for (int j = 0; j < 8; ++j) {                                                  \
        S[j] = fmaf(d_[j], S[j], kb_[j] * dv);                                     \
        o = fmaf(CUR.q[j], S[j], o);                                               \
    }                                                                              \
    o += __shfl_xor(o, 1); o += __shfl_xor(o, 2);                                  \
    o += __shfl_xor(o, 4); o += __shfl_xor(o, 8);                                  \
    if (kl == 0) obase[(size_t)(TT) * D_] = o;                                     \
} while (0)

    DR r0, r1;
    dload(r0, kc, qc, vc, knp, ampp, betp, kqbase, vbase, sbase, 0);
    for (int t = 0; t < T_; t += 2) {
        DSTEP(t,     r0, r1);
        DSTEP(t + 1, r1, r0);
    }
#undef DSTEP
}

// ---------------- combine fast/slow + RMSNorm + sigmoid gate -> bf16 ----------------
__global__ __launch_bounds__(128) void combine_k(
    const float* __restrict__ of, const float* __restrict__ os,
    const float* __restrict__ lm, const float* __restrict__ graw,
    const float* __restrict__ g2b, const float* __restrict__ onw,
    ushort_t* __restrict__ ocb)
{
    int blk = blockIdx.x;          // (b*T+t)*H + h
    int h = blk & 15, bt = blk >> 4;
    int b = bt / T_, t = bt % T_;
    int v = threadIdx.x;
    size_t idx = (size_t)bt * D_ + h * 128 + v;
    float l = lm[((size_t)(b * H_ + h)) * T_ + t];
    float o = l * of[idx] + (1.f - l) * os[idx];
    float s = o * o;
    #pragma unroll
    for (int off = 32; off > 0; off >>= 1) s += __shfl_xor(s, off);
    __shared__ float ws2[2];
    if ((threadIdx.x & 63) == 0) ws2[threadIdx.x >> 6] = s;
    __syncthreads();
    float tot = ws2[0] + ws2[1];
    float rms = sqrtf(tot / 128.f + 1e-5f);
    float g = graw[idx] + g2b[h * 128 + v];
    ocb[idx] = f2bf(o / rms * onw[v] * sigmoidf_(g));
}

extern "C" void kernel_launch(void* const* d_in, const int* in_sizes, int n_in,
                              void* d_out, int out_size, void* d_ws, size_t ws_size,
                              hipStream_t stream)
{
    const float* x        = (const float*)d_in[0];
    const float* wq       = (const float*)d_in[1];
    const float* wk       = (const float*)d_in[2];
    const float* wv       = (const float*)d_in[3];
    const float* conv_q_w = (const float*)d_in[4];
    const float* conv_k_w = (const float*)d_in[5];
    const float* conv_v_w = (const float*)d_in[6];
    const float* A_log    = (const float*)d_in[7];
    const float* dt_bias  = (const float*)d_in[8];
    const float* proxy_w  = (const float*)d_in[9];
    const float* unc_w    = (const float*)d_in[10];
    const float* he       = (const float*)d_in[11];
    const float* mlp_w1   = (const float*)d_in[12];
    const float* mlp_b1   = (const float*)d_in[13];
    const float* mlp_w2   = (const float*)d_in[14];
    const float* mlp_b2   = (const float*)d_in[15];
    const float* bb_w     = (const float*)d_in[16];
    const float* bb_b     = (const float*)d_in[17];
    const float* bd_w     = (const float*)d_in[18];
    const float* bd_b     = (const float*)d_in[19];
    const float* lam_w    = (const float*)d_in[20];
    const float* lam_b    = (const float*)d_in[21];
    const float* ab_w     = (const float*)d_in[22];
    const float* ab_b     = (const float*)d_in[23];
    const float* ad_w     = (const float*)d_in[24];
    const float* ad_b     = (const float*)d_in[25];
    const float* g1_w     = (const float*)d_in[26];
    const float* g2_w     = (const float*)d_in[27];
    const float* g2_b     = (const float*)d_in[28];
    const float* onorm_w  = (const float*)d_in[29];
    const float* wo       = (const float*)d_in[30];
    float* out = (float*)d_out;

    float* ws = (float*)d_ws;
    const size_t SZ = (size_t)BT_ * D_;          // 1,048,576
    float* qraw   = ws;
    float* kraw   = qraw + SZ;
    float* vraw   = kraw + SZ;
    float* qc     = vraw + SZ;
    float* kc     = qc + SZ;
    float* vc     = kc + SZ;
    float* graw   = vc + SZ;
    float* logits = graw + SZ;                   // 32768
    float* gtmp   = logits + 32768;              // 65536
    float* ent    = gtmp + 65536;                // 512
    float* bf     = ent + 512;
    float* bs     = bf + 8192;
    float* lm     = bs + 8192;
    float* af     = lm + 8192;
    float* as2    = af + 8192;
    float* kn     = as2 + 8192;
    float* gchan  = kn + 8192;                   // 2048
    float* fend   = gchan + 2048;
    ushort_t* xb    = (ushort_t*)fend;           // 1,048,576 bf16
    ushort_t* gtmpb = xb + SZ;                   // 65,536 bf16
    ushort_t* wT    = gtmpb + 65536;             // up to 4,194,304 bf16

    float* o_fast = qraw;                        // reuse (dead after conv)
    float* o_slow = kraw;
    ushort_t* ocb = (ushort_t*)vraw;

    dim3 blk256(256);
    const float QSCALE = 0.08838834764831845f;   // DK^-0.5

    // x -> bf16
    cvt_bf16<<<dim3(1024), blk256, 0, stream>>>(x, xb, (int)SZ);

    // projections (bf16 MFMA); weight transposed-converted into shared wT slot
    transcvt<<<dim3(64, 64), blk256, 0, stream>>>(wq, wT, 2048, 2048);
    gemm_bt<<<dim3(32, 8), blk256, 0, stream>>>(xb, wT, qraw, 512, 2048, 2048);
    transcvt<<<dim3(64, 64), blk256, 0, stream>>>(wk, wT, 2048, 2048);
    gemm_bt<<<dim3(32, 8), blk256, 0, stream>>>(xb, wT, kraw, 512, 2048, 2048);
    transcvt<<<dim3(64, 64), blk256, 0, stream>>>(wv, wT, 2048, 2048);
    gemm_bt<<<dim3(32, 8), blk256, 0, stream>>>(xb, wT, vraw, 512, 2048, 2048);
    transcvt<<<dim3(2, 64), blk256, 0, stream>>>(unc_w, wT, 2048, 64);
    gemm_bt<<<dim3(1, 8), blk256, 0, stream>>>(xb, wT, logits, 512, 64, 2048);
    transcvt<<<dim3(4, 64), blk256, 0, stream>>>(g1_w, wT, 2048, 128);
    gemm_bt<<<dim3(2, 8), blk256, 0, stream>>>(xb, wT, gtmp, 512, 128, 2048);
    cvt_bf16<<<dim3(64), blk256, 0, stream>>>(gtmp, gtmpb, 65536);
    transcvt<<<dim3(64, 4), blk256, 0, stream>>>(g2_w, wT, 128, 2048);
    gemm_bt<<<dim3(32, 8), blk256, 0, stream>>>(gtmpb, wT, graw, 512, 2048, 128);

    // conv + silu (q pre-scaled)
    conv_silu<<<dim3(8, BT_), blk256, 0, stream>>>(qraw, conv_q_w, qc, QSCALE);
    conv_silu<<<dim3(8, BT_), blk256, 0, stream>>>(kraw, conv_k_w, kc, 1.f);
    conv_silu<<<dim3(8, BT_), blk256, 0, stream>>>(vraw, conv_v_w, vc, 1.f);

    // small precomputations
    gchan_k<<<dim3(8), blk256, 0, stream>>>(A_log, dt_bias, gchan);
    entropy_k<<<dim3(BT_), dim3(64), 0, stream>>>(logits, ent);

    // per-(b,t,h) features + MLP
    feats_k<<<dim3(BT_ * H_), dim3(128), 0, stream>>>(
        kc, vc, proxy_w, ent, he, mlp_w1, mlp_b1, mlp_w2, mlp_b2,
        bb_w, bb_b, bd_w, bd_b, lam_w, lam_b, ab_w, ab_b, ad_w, ad_b,
        bf, bs, lm, af, as2, kn);

    // sequential delta rule: 2048 independent waves (fast+slow fused in grid)
    delta_wave<<<dim3(512), blk256, 0, stream>>>(qc, kc, vc, kn, bf, bs, af, as2,
                                                 gchan, o_fast, o_slow);

    // combine + rmsnorm + gate -> bf16
    combine_k<<<dim3(BT_ * H_), dim3(128), 0, stream>>>(o_fast, o_slow, lm, graw,
                                                        g2_b, onorm_w, ocb);

    // output projection
    transcvt<<<dim3(64, 64), blk256, 0, stream>>>(wo, wT, 2048, 2048);
    gemm_bt<<<dim3(32, 8), blk256, 0, stream>>>(ocb, wT, out, 512, 2048, 2048);
}

// Round 4
// 314.673 us; speedup vs baseline: 4.2796x; 1.4586x over previous
//
#include <hip/hip_runtime.h>
#include <hip/hip_bf16.h>
#include <math.h>

#define H_ 16
#define DK_ 128
#define DV_ 128
#define D_ 2048
#define T_ 256
#define B_ 2
#define BT_ 512

typedef __attribute__((ext_vector_type(8))) short short8v;
typedef __attribute__((ext_vector_type(4))) float float4v;
typedef unsigned short ushort_t;

__device__ __forceinline__ float sigmoidf_(float x){ return 1.f/(1.f+expf(-x)); }
__device__ __forceinline__ float siluf_(float x){ return x/(1.f+expf(-x)); }
__device__ __forceinline__ ushort_t f2bf(float f){
    __hip_bfloat16 h = __float2bfloat16(f);
    return *reinterpret_cast<ushort_t*>(&h);
}
// swizzled LDS index (shorts) for 64-row x 32-col bf16 tiles; k multiple of 8 in use
__device__ __forceinline__ int swz(int row, int k){
    return row * 32 + ((((k >> 3) ^ (row & 3)) << 3) | (k & 7));
}

// ---------------- fp32 -> bf16 elementwise ----------------
__global__ void cvt_bf16(const float* __restrict__ in, ushort_t* __restrict__ out, int n){
    int i = (blockIdx.x * 256 + threadIdx.x) * 4;
    if (i >= n) return;
    float4 v = *(const float4*)&in[i];
    union { ushort_t s[4]; unsigned long long u; } p;
    p.s[0] = f2bf(v.x); p.s[1] = f2bf(v.y); p.s[2] = f2bf(v.z); p.s[3] = f2bf(v.w);
    *(unsigned long long*)&out[i] = p.u;
}

// ---------------- strided cvt: C_big cols [6208,6336) -> gtmpb [512][128] bf16 ------
__global__ void cvt_strided(const float* __restrict__ Cb, ushort_t* __restrict__ out){
    int i = (blockIdx.x * 256 + threadIdx.x) * 4;   // 65536 total
    int m = i >> 7, c = i & 127;
    float4 v = *(const float4*)&Cb[(size_t)m * 6336 + 6208 + c];
    union { ushort_t s[4]; unsigned long long u; } p;
    p.s[0] = f2bf(v.x); p.s[1] = f2bf(v.y); p.s[2] = f2bf(v.z); p.s[3] = f2bf(v.w);
    *(unsigned long long*)&out[i] = p.u;
}

// ---------------- GEMM core: C[64x64 tile] = A_bf16[M,K] @ W_f32[K,Nst] -------------
// W transpose-converted inline into swizzled LDS; register ping-pong prefetch.
__device__ __forceinline__ void gemm_core(
    const ushort_t* __restrict__ A, int K,
    const float* __restrict__ W, int Nst, int nloc0,
    float* __restrict__ C, int Cst, int m0, int n0out)
{
    __shared__ ushort_t Asub[2048];
    __shared__ ushort_t Bsub[2048];
    const int tid = threadIdx.x;
    const int wid = tid >> 6, lane = tid & 63;
    const int wr = (wid >> 1) * 32, wc = (wid & 1) * 32;
    const int lr = lane & 15, lk = (lane >> 4) * 8;
    const int rowA = tid >> 2, kqA = tid & 3;       // A staging: b128 per thread
    const int nW = tid & 63, kqW = tid >> 6;        // W staging: 8 scalar rows

    float4v acc[2][2];
    #pragma unroll
    for (int i = 0; i < 2; ++i)
        #pragma unroll
        for (int j = 0; j < 2; ++j) acc[i][j] = (float4v){0.f, 0.f, 0.f, 0.f};

    short8v aRa, aRb;
    float wRa[8], wRb[8];

#define LOADT(AR, WR, KOFF) do {                                                   \
    AR = *(const short8v*)&A[(size_t)(m0 + rowA) * K + (KOFF) + kqA * 8];          \
    _Pragma("unroll")                                                              \
    for (int r = 0; r < 8; ++r)                                                    \
        WR[r] = W[(size_t)((KOFF) + kqW * 8 + r) * Nst + nloc0 + nW];              \
} while (0)
#define STORET(AR, WR) do {                                                        \
    *(short8v*)&Asub[swz(rowA, kqA * 8)] = AR;                                     \
    union { ushort_t s[8]; short8v v; } pk;                                        \
    _Pragma("unroll")                                                              \
    for (int r = 0; r < 8; ++r) pk.s[r] = f2bf(WR[r]);                             \
    *(short8v*)&Bsub[swz(nW, kqW * 8)] = pk.v;                                     \
} while (0)
#define FRAGMMA() do {                                                             \
    short8v af0 = *(const short8v*)&Asub[swz(wr + lr, lk)];                        \
    short8v af1 = *(const short8v*)&Asub[swz(wr + 16 + lr, lk)];                   \
    short8v bf0 = *(const short8v*)&Bsub[swz(wc + lr, lk)];                        \
    short8v bf1 = *(const short8v*)&Bsub[swz(wc + 16 + lr, lk)];                   \
    acc[0][0] = __builtin_amdgcn_mfma_f32_16x16x32_bf16(af0, bf0, acc[0][0],0,0,0);\
    acc[0][1] = __builtin_amdgcn_mfma_f32_16x16x32_bf16(af0, bf1, acc[0][1],0,0,0);\
    acc[1][0] = __builtin_amdgcn_mfma_f32_16x16x32_bf16(af1, bf0, acc[1][0],0,0,0);\
    acc[1][1] = __builtin_amdgcn_mfma_f32_16x16x32_bf16(af1, bf1, acc[1][1],0,0,0);\
} while (0)

    LOADT(aRa, wRa, 0);
    for (int k0 = 0; k0 < K; k0 += 64) {
        STORET(aRa, wRa);
        __syncthreads();
        if (k0 + 32 < K) LOADT(aRb, wRb, k0 + 32);
        FRAGMMA();
        __syncthreads();
        STORET(aRb, wRb);
        __syncthreads();
        if (k0 + 64 < K) LOADT(aRa, wRa, k0 + 64);
        FRAGMMA();
        __syncthreads();
    }
#undef LOADT
#undef STORET
#undef FRAGMMA
    const int lq = (lane >> 4) * 4;
    #pragma unroll
    for (int mi = 0; mi < 2; ++mi)
        #pragma unroll
        for (int ni = 0; ni < 2; ++ni)
            #pragma unroll
            for (int j = 0; j < 4; ++j)
                C[(size_t)(m0 + wr + mi * 16 + lq + j) * Cst + (n0out + wc + ni * 16 + lr)]
                    = acc[mi][ni][j];
}

// fused projection GEMM: N = 6336 = wq(2048) | wk(2048) | wv(2048) | unc(64) | g1(128)
__global__ __launch_bounds__(256) void gemm_proj(const ushort_t* __restrict__ A,
    const float* __restrict__ wq, const float* __restrict__ wk, const float* __restrict__ wv,
    const float* __restrict__ unc, const float* __restrict__ g1, float* __restrict__ C)
{
    int n0 = blockIdx.x * 64, m0 = blockIdx.y * 64;
    const float* W; int nloc, Nst;
    if (n0 < 2048)      { W = wq;  nloc = n0;        Nst = 2048; }
    else if (n0 < 4096) { W = wk;  nloc = n0 - 2048; Nst = 2048; }
    else if (n0 < 6144) { W = wv;  nloc = n0 - 4096; Nst = 2048; }
    else if (n0 < 6208) { W = unc; nloc = n0 - 6144; Nst = 64; }
    else                { W = g1;  nloc = n0 - 6208; Nst = 128; }
    gemm_core(A, 2048, W, Nst, nloc, C, 6336, m0, n0);
}

// single-weight GEMM: C[M,N] = A[M,K] @ W[K,N]
__global__ __launch_bounds__(256) void gemm_one(const ushort_t* __restrict__ A,
    const float* __restrict__ W, float* __restrict__ C, int N, int K)
{
    gemm_core(A, K, W, N, blockIdx.x * 64, C, N, blockIdx.y * 64, blockIdx.x * 64);
}

// ---------------- fused causal depthwise conv (K=4) + SiLU over q|k|v --------------
__global__ void conv_fused(const float* __restrict__ Cb,
    const float* __restrict__ wq, const float* __restrict__ wk, const float* __restrict__ wv,
    float* __restrict__ qc, float* __restrict__ kc, float* __restrict__ vc, float qscale)
{
    int c  = blockIdx.x * 256 + threadIdx.x;   // 0..6143
    int bt = blockIdx.y;
    int b  = bt / T_, t = bt % T_;
    int which = c >> 11, cloc = c & 2047;
    const float* w = which == 0 ? wq : which == 1 ? wk : wv;
    float* o = which == 0 ? qc : which == 1 ? kc : vc;
    float scale = which == 0 ? qscale : 1.f;
    float acc = 0.f;
    #pragma unroll
    for (int j = 0; j < 4; ++j) {
        int tt = t - 3 + j;
        if (tt >= 0) acc = fmaf(w[cloc * 4 + j], Cb[((size_t)(b * T_ + tt)) * 6336 + c], acc);
    }
    o[(size_t)bt * D_ + cloc] = siluf_(acc) * scale;
}

// ---------------- per-(b,t,h) features (+inline entropy) + tiny MLP ----------------
__global__ __launch_bounds__(128) void feats_k(
    const float* __restrict__ kc, const float* __restrict__ vc,
    const float* __restrict__ proxy, const float* __restrict__ Cb,
    const float* __restrict__ he,
    const float* __restrict__ w1, const float* __restrict__ b1,
    const float* __restrict__ w2, const float* __restrict__ b2,
    const float* __restrict__ bbw, const float* __restrict__ bbb,
    const float* __restrict__ bdw, const float* __restrict__ bdb,
    const float* __restrict__ lamw, const float* __restrict__ lamb,
    const float* __restrict__ abw, const float* __restrict__ abb,
    const float* __restrict__ adw, const float* __restrict__ adb,
    float* __restrict__ bf, float* __restrict__ bs, float* __restrict__ lm,
    float* __restrict__ af, float* __restrict__ as2, float* __restrict__ kn)
{
    int blk = blockIdx.x;          // (b*T+t)*H + h
    int h = blk & 15, bt = blk >> 4;
    int b = bt / T_, t = bt % T_;
    int v = threadIdx.x;           // 0..127
    __shared__ float kv[128];
    __shared__ float part[2][5];
    __shared__ float tot5[5];
    __shared__ float feats8[8];
    __shared__ float hf1[32];
    __shared__ float hf[32];
    __shared__ float entSh;

    // entropy of softmax over 64 logits (wave 0)
    if (v < 64) {
        float x = Cb[(size_t)bt * 6336 + 6144 + v];
        float m = x;
        #pragma unroll
        for (int o = 32; o > 0; o >>= 1) m = fmaxf(m, __shfl_xor(m, o));
        float e = expf(x - m);
        float s = e;
        #pragma unroll
        for (int o = 32; o > 0; o >>= 1) s += __shfl_xor(s, o);
        float lp = (x - m) - logf(s);
        float c = -expf(lp) * lp;
        #pragma unroll
        for (int o = 32; o > 0; o >>= 1) c += __shfl_xor(c, o);
        if (v == 0) entSh = c / logf(64.f);
    }

    size_t base = (size_t)bt * D_ + h * 128;
    float kval = kc[base + v];
    float vval = vc[base + v];
    kv[v] = kval;
    __syncthreads();
    float vhat = 0.f;
    #pragma unroll 4
    for (int k = 0; k < 128; ++k) vhat = fmaf(kv[k], proxy[k * 128 + v], vhat);

    float e = vval - vhat;
    float sums[5] = {kval * kval, vval * vval, vhat * vhat, vval * vhat, e * e};
    #pragma unroll
    for (int i = 0; i < 5; ++i) {
        float s = sums[i];
        #pragma unroll
        for (int o = 32; o > 0; o >>= 1) s += __shfl_xor(s, o);
        if ((threadIdx.x & 63) == 0) part[threadIdx.x >> 6][i] = s;
    }
    __syncthreads();
    if (threadIdx.x < 5) tot5[threadIdx.x] = part[0][threadIdx.x] + part[1][threadIdx.x];
    __syncthreads();
    if (threadIdx.x == 0) {
        float k2 = tot5[0], v2 = tot5[1], vh2 = tot5[2], vvh = tot5[3], e2 = tot5[4];
        float knorm = sqrtf(k2);
        float err_n = sqrtf(e2);
        float v_n = sqrtf(v2);
        float vh_n = sqrtf(vh2);
        feats8[0] = entSh;
        feats8[1] = err_n / (v_n + 1e-6f);
        feats8[2] = vvh / (v_n * vh_n + 1e-6f);
        feats8[3] = log1pf(err_n);
        feats8[4] = he[h * 4 + 0];
        feats8[5] = he[h * 4 + 1];
        feats8[6] = he[h * 4 + 2];
        feats8[7] = he[h * 4 + 3];
        kn[((size_t)(b * H_ + h)) * T_ + t] = knorm;
    }
    __syncthreads();
    if (threadIdx.x < 32) {
        float a = b1[threadIdx.x];
        #pragma unroll
        for (int j = 0; j < 8; ++j) a = fmaf(feats8[j], w1[j * 32 + threadIdx.x], a);
        hf1[threadIdx.x] = siluf_(a);
    }
    __syncthreads();
    if (threadIdx.x < 32) {
        float a = b2[threadIdx.x];
        #pragma unroll
        for (int j = 0; j < 32; ++j) a = fmaf(hf1[j], w2[j * 32 + threadIdx.x], a);
        hf[threadIdx.x] = siluf_(a);
    }
    __syncthreads();
    if (threadIdx.x == 0) {
        float bb = bbb[0], bd = bdb[0], lv = lamb[0], ab = abb[0], ad = adb[0];
        #pragma unroll
        for (int j = 0; j < 32; ++j) {
            float hj = hf[j];
            bb = fmaf(hj, bbw[j], bb);
            bd = fmaf(hj, bdw[j], bd);
            lv = fmaf(hj, lamw[j], lv);
            ab = fmaf(hj, abw[j], ab);
            ad = fmaf(hj, adw[j], ad);
        }
        size_t o = ((size_t)(b * H_ + h)) * T_ + t;
        bf[o]  = sigmoidf_(bb + bd);
        bs[o]  = sigmoidf_(bb - bd);
        lm[o]  = sigmoidf_(lv);
        af[o]  = sigmoidf_(ab + ad);
        as2[o] = sigmoidf_(ab - ad);
    }
}

// ---------------- precompute scan operands: ku[bh][t][k], d[rule][bh][t][k], qkb ----
__global__ __launch_bounds__(128) void precomp_k(
    const float* __restrict__ kc, const float* __restrict__ qc,
    const float* __restrict__ kn,
    const float* __restrict__ af, const float* __restrict__ as2,
    const float* __restrict__ bf, const float* __restrict__ bs,
    const float* __restrict__ A_log, const float* __restrict__ dt_bias,
    float* __restrict__ kuA, float* __restrict__ dA, float* __restrict__ qkbA)
{
    const int t = blockIdx.x;
    const int y = blockIdx.y;                // rule*32 + b*16 + h
    const int rule = y >> 5, b = (y >> 4) & 1, h = y & 15;
    const int k = threadIdx.x;
    const int sb = (b * 16 + h) * 256 + t;
    const float knv = kn[sb];
    const float am  = (rule ? as2 : af)[sb];
    const float btv = (rule ? bs : bf)[sb];
    const size_t idx = (size_t)(b * 256 + t) * D_ + h * 128 + k;
    const float kuv = kc[idx] / (knv + 1e-6f);
    float x = dt_bias[h * 128 + k];
    float sp = (x > 20.f) ? x : log1pf(expf(x));
    float gch = -expf(A_log[h]) * sp * 1.44269504088896f;   // * log2(e)
    float dv = exp2f(gch * am);
    if (rule == 0) kuA[((size_t)(b * 16 + h) * 256 + t) * 128 + k] = kuv;
    dA[((size_t)y * 256 + t) * 128 + k] = dv;
    float p = qc[idx] * kuv;
    #pragma unroll
    for (int o = 32; o > 0; o >>= 1) p += __shfl_xor(p, o);
    __shared__ float pp[2];
    if ((k & 63) == 0) pp[k >> 6] = p;
    __syncthreads();
    if (k == 0) qkbA[(size_t)y * 256 + t] = (pp[0] + pp[1]) * btv;
}

// ---------------- delta-rule scan: pure registers + precomputed operands -----------
// 2048 waves: rule(2) x b(2) x h(16) x v-chunk(32); wave = 16 k-lanes x 4 v-groups.
struct DR2 { float ku[8], d[8], q[8], v, bt, qkb; };

__device__ __forceinline__ void dload2(DR2& r,
    const float* __restrict__ pku, const float* __restrict__ pd,
    const float* __restrict__ pq, const float* __restrict__ pv,
    const float* __restrict__ pbt, const float* __restrict__ pqkb, int t)
{
    const float* a = pku + (size_t)t * 128;
    float4 x0 = *(const float4*)a, x1 = *(const float4*)(a + 4);
    r.ku[0]=x0.x; r.ku[1]=x0.y; r.ku[2]=x0.z; r.ku[3]=x0.w;
    r.ku[4]=x1.x; r.ku[5]=x1.y; r.ku[6]=x1.z; r.ku[7]=x1.w;
    const float* bp = pd + (size_t)t * 128;
    float4 y0 = *(const float4*)bp, y1 = *(const float4*)(bp + 4);
    r.d[0]=y0.x; r.d[1]=y0.y; r.d[2]=y0.z; r.d[3]=y0.w;
    r.d[4]=y1.x; r.d[5]=y1.y; r.d[6]=y1.z; r.d[7]=y1.w;
    const float* cp = pq + (size_t)t * D_;
    float4 z0 = *(const float4*)cp, z1 = *(const float4*)(cp + 4);
    r.q[0]=z0.x; r.q[1]=z0.y; r.q[2]=z0.z; r.q[3]=z0.w;
    r.q[4]=z1.x; r.q[5]=z1.y; r.q[6]=z1.z; r.q[7]=z1.w;
    r.v   = pv[(size_t)t * D_];
    r.bt  = pbt[t];
    r.qkb = pqkb[t];
}

__global__ __launch_bounds__(256) void delta_wave2(
    const float* __restrict__ qc, const float* __restrict__ vc,
    const float* __restrict__ kuA, const float* __restrict__ dA,
    const float* __restrict__ qkbA,
    const float* __restrict__ bf, const float* __restrict__ bs,
    float* __restrict__ o_fast, float* __restrict__ o_slow)
{
    const int w     = blockIdx.x * 4 + (threadIdx.x >> 6);
    const int lane  = threadIdx.x & 63;
    const int chunk = w & 31;
    const int h     = (w >> 5) & 15;
    const int b     = (w >> 9) & 1;
    const int rule  = w >> 10;
    const int kl    = lane & 15;
    const int vg    = lane >> 4;
    const int vcol  = chunk * 4 + vg;
    const int rbh   = rule * 32 + b * 16 + h;

    const float* __restrict__ pku  = kuA + ((size_t)(b * 16 + h) * 256) * 128 + kl * 8;
    const float* __restrict__ pd   = dA  + ((size_t)rbh * 256) * 128 + kl * 8;
    const float* __restrict__ pq   = qc + (size_t)b * T_ * D_ + h * 128 + kl * 8;
    const float* __restrict__ pv   = vc + (size_t)b * T_ * D_ + h * 128 + vcol;
    const float* __restrict__ pbt  = (rule ? bs : bf) + (size_t)(b * 16 + h) * 256;
    const float* __restrict__ pqkb = qkbA + (size_t)rbh * 256;
    float* __restrict__ obase = (rule ? o_slow : o_fast)
                                + (size_t)b * T_ * D_ + h * 128 + vcol;

    float S[8];
    #pragma unroll
    for (int j = 0; j < 8; ++j) S[j] = 0.f;

#define DSTEP(TT, CUR, NXT) do {                                                   \
    float vp = 0.f, oq = 0.f;                                                      \
    _Pragma("unroll")                                                              \
    for (int j = 0; j < 8; ++j) {                                                  \
        vp = fmaf(CUR.ku[j] * CUR.d[j], S[j], vp);                                 \
        oq = fmaf(CUR.q[j]  * CUR.d[j], S[j], oq);                                 \
    }                                                                              \
    if ((TT) + 1 < T_) dload2(NXT, pku, pd, pq, pv, pbt, pqkb, (TT) + 1);          \
    vp += __shfl_xor(vp, 1); oq += __shfl_xor(oq, 1);                              \
    vp += __shfl_xor(vp, 2); oq += __shfl_xor(oq, 2);                              \
    vp += __shfl_xor(vp, 4); oq += __shfl_xor(oq, 4);                              \
    vp += __shfl_xor(vp, 8); oq += __shfl_xor(oq, 8);                              \
    float dv = CUR.v - vp;                                                         \
    float o = fmaf(CUR.qkb, dv, oq);                                               \
    float btdv = CUR.bt * dv;                                                      \
    _Pragma("unroll")                                                              \
    for (int j = 0; j < 8; ++j)                                                    \
        S[j] = fmaf(CUR.d[j], S[j], CUR.ku[j] * btdv);                             \
    if (kl == 0) obase[(size_t)(TT) * D_] = o;                                     \
} while (0)

    DR2 r0, r1;
    dload2(r0, pku, pd, pq, pv, pbt, pqkb, 0);
    for (int t = 0; t < T_; t += 2) {
        DSTEP(t,     r0, r1);
        DSTEP(t + 1, r1, r0);
    }
#undef DSTEP
}

// ---------------- combine fast/slow + RMSNorm + sigmoid gate -> bf16 ----------------
__global__ __launch_bounds__(128) void combine_k(
    const float* __restrict__ of, const float* __restrict__ os,
    const float* __restrict__ lm, const float* __restrict__ graw,
    const float* __restrict__ g2b, const float* __restrict__ onw,
    ushort_t* __restrict__ ocb)
{
    int blk = blockIdx.x;          // (b*T+t)*H + h
    int h = blk & 15, bt = blk >> 4;
    int b = bt / T_, t = bt % T_;
    int v = threadIdx.x;
    size_t idx = (size_t)bt * D_ + h * 128 + v;
    float l = lm[((size_t)(b * H_ + h)) * T_ + t];
    float o = l * of[idx] + (1.f - l) * os[idx];
    float s = o * o;
    #pragma unroll
    for (int off = 32; off > 0; off >>= 1) s += __shfl_xor(s, off);
    __shared__ float ws2[2];
    if ((threadIdx.x & 63) == 0) ws2[threadIdx.x >> 6] = s;
    __syncthreads();
    float tot = ws2[0] + ws2[1];
    float rms = sqrtf(tot / 128.f + 1e-5f);
    float g = graw[idx] + g2b[h * 128 + v];
    ocb[idx] = f2bf(o / rms * onw[v] * sigmoidf_(g));
}

extern "C" void kernel_launch(void* const* d_in, const int* in_sizes, int n_in,
                              void* d_out, int out_size, void* d_ws, size_t ws_size,
                              hipStream_t stream)
{
    const float* x        = (const float*)d_in[0];
    const float* wq       = (const float*)d_in[1];
    const float* wk       = (const float*)d_in[2];
    const float* wv       = (const float*)d_in[3];
    const float* conv_q_w = (const float*)d_in[4];
    const float* conv_k_w = (const float*)d_in[5];
    const float* conv_v_w = (const float*)d_in[6];
    const float* A_log    = (const float*)d_in[7];
    const float* dt_bias  = (const float*)d_in[8];
    const float* proxy_w  = (const float*)d_in[9];
    const float* unc_w    = (const float*)d_in[10];
    const float* he       = (const float*)d_in[11];
    const float* mlp_w1   = (const float*)d_in[12];
    const float* mlp_b1   = (const float*)d_in[13];
    const float* mlp_w2   = (const float*)d_in[14];
    const float* mlp_b2   = (const float*)d_in[15];
    const float* bb_w     = (const float*)d_in[16];
    const float* bb_b     = (const float*)d_in[17];
    const float* bd_w     = (const float*)d_in[18];
    const float* bd_b     = (const float*)d_in[19];
    const float* lam_w    = (const float*)d_in[20];
    const float* lam_b    = (const float*)d_in[21];
    const float* ab_w     = (const float*)d_in[22];
    const float* ab_b     = (const float*)d_in[23];
    const float* ad_w     = (const float*)d_in[24];
    const float* ad_b     = (const float*)d_in[25];
    const float* g1_w     = (const float*)d_in[26];
    const float* g2_w     = (const float*)d_in[27];
    const float* g2_b     = (const float*)d_in[28];
    const float* onorm_w  = (const float*)d_in[29];
    const float* wo       = (const float*)d_in[30];
    float* out = (float*)d_out;

    float* ws = (float*)d_ws;
    const size_t SZ = (size_t)BT_ * D_;              // 1,048,576
    float* C_big = ws;                               // 512*6336 = 3,244,032
    float* qc    = C_big + (size_t)512 * 6336;
    float* kc    = qc + SZ;
    float* vc    = kc + SZ;
    float* graw  = vc + SZ;
    float* bf    = graw + SZ;                        // 6 x 8192 scalars
    float* bs    = bf + 8192;
    float* lm    = bs + 8192;
    float* af    = lm + 8192;
    float* as2   = af + 8192;
    float* kn    = as2 + 8192;
    float* qkbA  = kn + 8192;                        // 64*256 = 16,384
    float* kuA   = qkbA + 16384;                     // 2*16*256*128 = 1,048,576
    float* dA    = kuA + 1048576;                    // 2*2*16*256*128 = 2,097,152
    float* fend  = dA + 2097152;
    ushort_t* xb    = (ushort_t*)fend;               // 1,048,576 bf16
    ushort_t* gtmpb = xb + SZ;                       // 65,536 bf16
    // total ~= 45 MB

    float* o_fast = C_big;                           // overlay (dead after feats_k)
    float* o_slow = C_big + SZ;
    ushort_t* ocb = xb;                              // overlay (dead after gemm_proj)

    dim3 blk256(256);
    const float QSCALE = 0.08838834764831845f;       // DK^-0.5

    // 1. x -> bf16
    cvt_bf16<<<dim3(1024), blk256, 0, stream>>>(x, xb, (int)SZ);
    // 2. fused projections: [512][6336] = xb @ [wq|wk|wv|unc|g1]
    gemm_proj<<<dim3(99, 8), blk256, 0, stream>>>(xb, wq, wk, wv, unc_w, g1_w, C_big);
    // 3. gtmp cols -> bf16
    cvt_strided<<<dim3(64), blk256, 0, stream>>>(C_big, gtmpb);
    // 4. graw = gtmpb @ g2_w
    gemm_one<<<dim3(32, 8), blk256, 0, stream>>>(gtmpb, g2_w, graw, 2048, 128);
    // 5. conv + silu (q pre-scaled)
    conv_fused<<<dim3(24, BT_), blk256, 0, stream>>>(C_big, conv_q_w, conv_k_w, conv_v_w,
                                                     qc, kc, vc, QSCALE);
    // 6. per-(b,t,h) features + MLP (+entropy inline)
    feats_k<<<dim3(BT_ * H_), dim3(128), 0, stream>>>(
        kc, vc, proxy_w, C_big, he, mlp_w1, mlp_b1, mlp_w2, mlp_b2,
        bb_w, bb_b, bd_w, bd_b, lam_w, lam_b, ab_w, ab_b, ad_w, ad_b,
        bf, bs, lm, af, as2, kn);
    // 7. precompute ku / d / qkb
    precomp_k<<<dim3(256, 64), dim3(128), 0, stream>>>(
        kc, qc, kn, af, as2, bf, bs, A_log, dt_bias, kuA, dA, qkbA);
    // 8. delta-rule scan (fast+slow fused in grid)
    delta_wave2<<<dim3(512), blk256, 0, stream>>>(qc, vc, kuA, dA, qkbA, bf, bs,
                                                  o_fast, o_slow);
    // 9. combine + rmsnorm + gate -> bf16
    combine_k<<<dim3(BT_ * H_), dim3(128), 0, stream>>>(o_fast, o_slow, lm, graw,
                                                        g2_b, onorm_w, ocb);
    // 10. output projection
    gemm_one<<<dim3(32, 8), blk256, 0, stream>>>(ocb, wo, out, 2048, 2048);
}

// Round 5
// 307.020 us; speedup vs baseline: 4.3862x; 1.0249x over previous
//
#include <hip/hip_runtime.h>
#include <hip/hip_bf16.h>
#include <math.h>

#define H_ 16
#define DK_ 128
#define DV_ 128
#define D_ 2048
#define T_ 256
#define B_ 2
#define BT_ 512

typedef __attribute__((ext_vector_type(8))) short short8v;
typedef __attribute__((ext_vector_type(4))) float float4v;
typedef unsigned short ushort_t;

__device__ __forceinline__ float sigmoidf_(float x){ return 1.f/(1.f+expf(-x)); }
__device__ __forceinline__ float siluf_(float x){ return x/(1.f+expf(-x)); }
__device__ __forceinline__ ushort_t f2bf(float f){
    __hip_bfloat16 h = __float2bfloat16(f);
    return *reinterpret_cast<ushort_t*>(&h);
}
// swizzled LDS index (shorts) for 64-row x 32-col bf16 tiles; k multiple of 8 in use
__device__ __forceinline__ int swz(int row, int k){
    return row * 32 + ((((k >> 3) ^ (row & 3)) << 3) | (k & 7));
}

// ---------------- fp32 -> bf16 elementwise ----------------
__global__ void cvt_bf16(const float* __restrict__ in, ushort_t* __restrict__ out, int n){
    int i = (blockIdx.x * 256 + threadIdx.x) * 4;
    if (i >= n) return;
    float4 v = *(const float4*)&in[i];
    union { ushort_t s[4]; unsigned long long u; } p;
    p.s[0] = f2bf(v.x); p.s[1] = f2bf(v.y); p.s[2] = f2bf(v.z); p.s[3] = f2bf(v.w);
    *(unsigned long long*)&out[i] = p.u;
}

// ---------------- strided cvt: C_big cols [6208,6336) -> gtmpb [512][128] bf16 ------
__global__ void cvt_strided(const float* __restrict__ Cb, ushort_t* __restrict__ out){
    int i = (blockIdx.x * 256 + threadIdx.x) * 4;   // 65536 total
    int m = i >> 7, c = i & 127;
    float4 v = *(const float4*)&Cb[(size_t)m * 6336 + 6208 + c];
    union { ushort_t s[4]; unsigned long long u; } p;
    p.s[0] = f2bf(v.x); p.s[1] = f2bf(v.y); p.s[2] = f2bf(v.z); p.s[3] = f2bf(v.w);
    *(unsigned long long*)&out[i] = p.u;
}

// ---------------- GEMM core: C[64x64 tile] = A_bf16[M,K] @ W_f32[K,Nst] -------------
// W transpose-converted inline into swizzled LDS; register ping-pong prefetch.
__device__ __forceinline__ void gemm_core(
    const ushort_t* __restrict__ A, int K,
    const float* __restrict__ W, int Nst, int nloc0,
    float* __restrict__ C, int Cst, int m0, int n0out)
{
    __shared__ ushort_t Asub[2048];
    __shared__ ushort_t Bsub[2048];
    const int tid = threadIdx.x;
    const int wid = tid >> 6, lane = tid & 63;
    const int wr = (wid >> 1) * 32, wc = (wid & 1) * 32;
    const int lr = lane & 15, lk = (lane >> 4) * 8;
    const int rowA = tid >> 2, kqA = tid & 3;       // A staging: b128 per thread
    const int nW = tid & 63, kqW = tid >> 6;        // W staging: 8 scalar rows

    float4v acc[2][2];
    #pragma unroll
    for (int i = 0; i < 2; ++i)
        #pragma unroll
        for (int j = 0; j < 2; ++j) acc[i][j] = (float4v){0.f, 0.f, 0.f, 0.f};

    short8v aRa, aRb;
    float wRa[8], wRb[8];

#define LOADT(AR, WR, KOFF) do {                                                   \
    AR = *(const short8v*)&A[(size_t)(m0 + rowA) * K + (KOFF) + kqA * 8];          \
    _Pragma("unroll")                                                              \
    for (int r = 0; r < 8; ++r)                                                    \
        WR[r] = W[(size_t)((KOFF) + kqW * 8 + r) * Nst + nloc0 + nW];              \
} while (0)
#define STORET(AR, WR) do {                                                        \
    *(short8v*)&Asub[swz(rowA, kqA * 8)] = AR;                                     \
    union { ushort_t s[8]; short8v v; } pk;                                        \
    _Pragma("unroll")                                                              \
    for (int r = 0; r < 8; ++r) pk.s[r] = f2bf(WR[r]);                             \
    *(short8v*)&Bsub[swz(nW, kqW * 8)] = pk.v;                                     \
} while (0)
#define FRAGMMA() do {                                                             \
    short8v af0 = *(const short8v*)&Asub[swz(wr + lr, lk)];                        \
    short8v af1 = *(const short8v*)&Asub[swz(wr + 16 + lr, lk)];                   \
    short8v bf0 = *(const short8v*)&Bsub[swz(wc + lr, lk)];                        \
    short8v bf1 = *(const short8v*)&Bsub[swz(wc + 16 + lr, lk)];                   \
    acc[0][0] = __builtin_amdgcn_mfma_f32_16x16x32_bf16(af0, bf0, acc[0][0],0,0,0);\
    acc[0][1] = __builtin_amdgcn_mfma_f32_16x16x32_bf16(af0, bf1, acc[0][1],0,0,0);\
    acc[1][0] = __builtin_amdgcn_mfma_f32_16x16x32_bf16(af1, bf0, acc[1][0],0,0,0);\
    acc[1][1] = __builtin_amdgcn_mfma_f32_16x16x32_bf16(af1, bf1, acc[1][1],0,0,0);\
} while (0)

    LOADT(aRa, wRa, 0);
    for (int k0 = 0; k0 < K; k0 += 64) {
        STORET(aRa, wRa);
        __syncthreads();
        if (k0 + 32 < K) LOADT(aRb, wRb, k0 + 32);
        FRAGMMA();
        __syncthreads();
        STORET(aRb, wRb);
        __syncthreads();
        if (k0 + 64 < K) LOADT(aRa, wRa, k0 + 64);
        FRAGMMA();
        __syncthreads();
    }
#undef LOADT
#undef STORET
#undef FRAGMMA
    const int lq = (lane >> 4) * 4;
    #pragma unroll
    for (int mi = 0; mi < 2; ++mi)
        #pragma unroll
        for (int ni = 0; ni < 2; ++ni)
            #pragma unroll
            for (int j = 0; j < 4; ++j)
                C[(size_t)(m0 + wr + mi * 16 + lq + j) * Cst + (n0out + wc + ni * 16 + lr)]
                    = acc[mi][ni][j];
}

// fused projection GEMM: N = 6336 = wq(2048) | wk(2048) | wv(2048) | unc(64) | g1(128)
__global__ __launch_bounds__(256) void gemm_proj(const ushort_t* __restrict__ A,
    const float* __restrict__ wq, const float* __restrict__ wk, const float* __restrict__ wv,
    const float* __restrict__ unc, const float* __restrict__ g1, float* __restrict__ C)
{
    int n0 = blockIdx.x * 64, m0 = blockIdx.y * 64;
    const float* W; int nloc, Nst;
    if (n0 < 2048)      { W = wq;  nloc = n0;        Nst = 2048; }
    else if (n0 < 4096) { W = wk;  nloc = n0 - 2048; Nst = 2048; }
    else if (n0 < 6144) { W = wv;  nloc = n0 - 4096; Nst = 2048; }
    else if (n0 < 6208) { W = unc; nloc = n0 - 6144; Nst = 64; }
    else                { W = g1;  nloc = n0 - 6208; Nst = 128; }
    gemm_core(A, 2048, W, Nst, nloc, C, 6336, m0, n0);
}

// single-weight GEMM: C[M,N] = A[M,K] @ W[K,N]
__global__ __launch_bounds__(256) void gemm_one(const ushort_t* __restrict__ A,
    const float* __restrict__ W, float* __restrict__ C, int N, int K)
{
    gemm_core(A, K, W, N, blockIdx.x * 64, C, N, blockIdx.y * 64, blockIdx.x * 64);
}

// ---------------- fused causal depthwise conv (K=4) + SiLU over q|k|v --------------
// also emits bf16 copy of k-section (for the vhat GEMM)
__global__ void conv_fused(const float* __restrict__ Cb,
    const float* __restrict__ wq, const float* __restrict__ wk, const float* __restrict__ wv,
    float* __restrict__ qc, float* __restrict__ kc, float* __restrict__ vc,
    ushort_t* __restrict__ kcb, float qscale)
{
    int c  = blockIdx.x * 256 + threadIdx.x;   // 0..6143
    int bt = blockIdx.y;
    int b  = bt / T_, t = bt % T_;
    int which = c >> 11, cloc = c & 2047;
    const float* w = which == 0 ? wq : which == 1 ? wk : wv;
    float* o = which == 0 ? qc : which == 1 ? kc : vc;
    float scale = which == 0 ? qscale : 1.f;
    float acc = 0.f;
    #pragma unroll
    for (int j = 0; j < 4; ++j) {
        int tt = t - 3 + j;
        if (tt >= 0) acc = fmaf(w[cloc * 4 + j], Cb[((size_t)(b * T_ + tt)) * 6336 + c], acc);
    }
    float r = siluf_(acc) * scale;
    o[(size_t)bt * D_ + cloc] = r;
    if (which == 1) kcb[(size_t)bt * D_ + cloc] = f2bf(r);
}

// ---------------- g_chan (pre-scaled by log2(e) for exp2f) ----------------
__global__ void gchan_k(const float* __restrict__ A_log, const float* __restrict__ dt_bias,
                        float* __restrict__ gchan)
{
    int i = blockIdx.x * 256 + threadIdx.x;
    int h = i >> 7;
    float x = dt_bias[i];
    float sp = (x > 20.f) ? x : log1pf(expf(x));
    gchan[i] = -expf(A_log[h]) * sp * 1.44269504088896f;
}

// ---------------- per-(b,t,h) features (+inline entropy) + tiny MLP ----------------
__global__ __launch_bounds__(128) void feats_k(
    const float* __restrict__ kc, const float* __restrict__ vc,
    const float* __restrict__ vhatA, const float* __restrict__ Cb,
    const float* __restrict__ he,
    const float* __restrict__ w1, const float* __restrict__ b1,
    const float* __restrict__ w2, const float* __restrict__ b2,
    const float* __restrict__ bbw, const float* __restrict__ bbb,
    const float* __restrict__ bdw, const float* __restrict__ bdb,
    const float* __restrict__ lamw, const float* __restrict__ lamb,
    const float* __restrict__ abw, const float* __restrict__ abb,
    const float* __restrict__ adw, const float* __restrict__ adb,
    float* __restrict__ bf, float* __restrict__ bs, float* __restrict__ lm,
    float* __restrict__ af, float* __restrict__ as2, float* __restrict__ kn)
{
    int blk = blockIdx.x;          // (b*T+t)*H + h
    int h = blk & 15, bt = blk >> 4;
    int b = bt / T_, t = bt % T_;
    int v = threadIdx.x;           // 0..127
    __shared__ float part[2][5];
    __shared__ float tot5[5];
    __shared__ float feats8[8];
    __shared__ float hf1[32];
    __shared__ float hf[32];
    __shared__ float entSh;

    // entropy of softmax over 64 logits (wave 0)
    if (v < 64) {
        float x = Cb[(size_t)bt * 6336 + 6144 + v];
        float m = x;
        #pragma unroll
        for (int o = 32; o > 0; o >>= 1) m = fmaxf(m, __shfl_xor(m, o));
        float e = expf(x - m);
        float s = e;
        #pragma unroll
        for (int o = 32; o > 0; o >>= 1) s += __shfl_xor(s, o);
        float lp = (x - m) - logf(s);
        float c = -expf(lp) * lp;
        #pragma unroll
        for (int o = 32; o > 0; o >>= 1) c += __shfl_xor(c, o);
        if (v == 0) entSh = c / logf(64.f);
    }

    size_t base = (size_t)bt * D_ + h * 128;
    float kval = kc[base + v];
    float vval = vc[base + v];
    float vhat = vhatA[(size_t)blk * 128 + v];

    float e = vval - vhat;
    float sums[5] = {kval * kval, vval * vval, vhat * vhat, vval * vhat, e * e};
    #pragma unroll
    for (int i = 0; i < 5; ++i) {
        float s = sums[i];
        #pragma unroll
        for (int o = 32; o > 0; o >>= 1) s += __shfl_xor(s, o);
        if ((threadIdx.x & 63) == 0) part[threadIdx.x >> 6][i] = s;
    }
    __syncthreads();
    if (threadIdx.x < 5) tot5[threadIdx.x] = part[0][threadIdx.x] + part[1][threadIdx.x];
    __syncthreads();
    if (threadIdx.x == 0) {
        float k2 = tot5[0], v2 = tot5[1], vh2 = tot5[2], vvh = tot5[3], e2 = tot5[4];
        float knorm = sqrtf(k2);
        float err_n = sqrtf(e2);
        float v_n = sqrtf(v2);
        float vh_n = sqrtf(vh2);
        feats8[0] = entSh;
        feats8[1] = err_n / (v_n + 1e-6f);
        feats8[2] = vvh / (v_n * vh_n + 1e-6f);
        feats8[3] = log1pf(err_n);
        feats8[4] = he[h * 4 + 0];
        feats8[5] = he[h * 4 + 1];
        feats8[6] = he[h * 4 + 2];
        feats8[7] = he[h * 4 + 3];
        kn[((size_t)(b * H_ + h)) * T_ + t] = knorm;
    }
    __syncthreads();
    if (threadIdx.x < 32) {
        float a = b1[threadIdx.x];
        #pragma unroll
        for (int j = 0; j < 8; ++j) a = fmaf(feats8[j], w1[j * 32 + threadIdx.x], a);
        hf1[threadIdx.x] = siluf_(a);
    }
    __syncthreads();
    if (threadIdx.x < 32) {
        float a = b2[threadIdx.x];
        #pragma unroll
        for (int j = 0; j < 32; ++j) a = fmaf(hf1[j], w2[j * 32 + threadIdx.x], a);
        hf[threadIdx.x] = siluf_(a);
    }
    __syncthreads();
    if (threadIdx.x == 0) {
        float bb = bbb[0], bd = bdb[0], lv = lamb[0], ab = abb[0], ad = adb[0];
        #pragma unroll
        for (int j = 0; j < 32; ++j) {
            float hj = hf[j];
            bb = fmaf(hj, bbw[j], bb);
            bd = fmaf(hj, bdw[j], bd);
            lv = fmaf(hj, lamw[j], lv);
            ab = fmaf(hj, abw[j], ab);
            ad = fmaf(hj, adw[j], ad);
        }
        size_t o = ((size_t)(b * H_ + h)) * T_ + t;
        bf[o]  = sigmoidf_(bb + bd);
        bs[o]  = sigmoidf_(bb - bd);
        lm[o]  = sigmoidf_(lv);
        af[o]  = sigmoidf_(ab + ad);
        as2[o] = sigmoidf_(ab - ad);
    }
}

// ---------------- precompute scan operands: ku[bh][t][k], d[rule][bh][t][k], qkb ----
__global__ __launch_bounds__(128) void precomp_k(
    const float* __restrict__ kc, const float* __restrict__ qc,
    const float* __restrict__ kn,
    const float* __restrict__ af, const float* __restrict__ as2,
    const float* __restrict__ bf, const float* __restrict__ bs,
    const float* __restrict__ gchan,
    float* __restrict__ kuA, float* __restrict__ dA, float* __restrict__ qkbA)
{
    const int t = blockIdx.x;
    const int y = blockIdx.y;                // rule*32 + b*16 + h
    const int rule = y >> 5, b = (y >> 4) & 1, h = y & 15;
    const int k = threadIdx.x;
    const int sb = (b * 16 + h) * 256 + t;
    const float knv = kn[sb];
    const float am  = (rule ? as2 : af)[sb];
    const float btv = (rule ? bs : bf)[sb];
    const size_t idx = (size_t)(b * 256 + t) * D_ + h * 128 + k;
    const float kuv = kc[idx] / (knv + 1e-6f);
    float dv = exp2f(gchan[h * 128 + k] * am);
    if (rule == 0) kuA[((size_t)(b * 16 + h) * 256 + t) * 128 + k] = kuv;
    dA[((size_t)y * 256 + t) * 128 + k] = dv;
    float p = qc[idx] * kuv;
    #pragma unroll
    for (int o = 32; o > 0; o >>= 1) p += __shfl_xor(p, o);
    __shared__ float pp[2];
    if ((k & 63) == 0) pp[k >> 6] = p;
    __syncthreads();
    if (k == 0) qkbA[(size_t)y * 256 + t] = (pp[0] + pp[1]) * btv;
}

// ---------------- delta-rule scan: pure registers, XCD-swizzled, 4096 waves --------
// wave = 32 k-lanes x 2 v-groups; lane owns S[4k][1v]. 64 v-chunks per (rule,b,h).
struct DR3 { float ku[4], d[4], q[4], v, bt, qkb; };

__device__ __forceinline__ void dload3(DR3& r,
    const float* __restrict__ pku, const float* __restrict__ pd,
    const float* __restrict__ pq, const float* __restrict__ pv,
    const float* __restrict__ pbt, const float* __restrict__ pqkb, int t)
{
    float4 a = *(const float4*)(pku + (size_t)t * 128);
    r.ku[0]=a.x; r.ku[1]=a.y; r.ku[2]=a.z; r.ku[3]=a.w;
    float4 b = *(const float4*)(pd + (size_t)t * 128);
    r.d[0]=b.x; r.d[1]=b.y; r.d[2]=b.z; r.d[3]=b.w;
    float4 c = *(const float4*)(pq + (size_t)t * D_);
    r.q[0]=c.x; r.q[1]=c.y; r.q[2]=c.z; r.q[3]=c.w;
    r.v   = pv[(size_t)t * D_];
    r.bt  = pbt[t];
    r.qkb = pqkb[t];
}

__global__ __launch_bounds__(256) void delta_wave3(
    const float* __restrict__ qc, const float* __restrict__ vc,
    const float* __restrict__ kuA, const float* __restrict__ dA,
    const float* __restrict__ qkbA,
    const float* __restrict__ bf, const float* __restrict__ bs,
    float* __restrict__ o_fast, float* __restrict__ o_slow)
{
    const int p  = blockIdx.x;                    // 0..1023
    const int lb = (p & 7) * 128 + (p >> 3);      // XCD-contiguous logical block
    const int bh = lb >> 5;                       // 0..31 ; 4 bh per XCD
    const int u  = (lb & 31) * 4 + (threadIdx.x >> 6);   // 0..127
    const int rule  = u >> 6;
    const int chunk = u & 63;
    const int b = bh >> 4, h = bh & 15;
    const int lane = threadIdx.x & 63;
    const int kl = lane & 31;                     // k-lane: owns k [kl*4, kl*4+4)
    const int vg = lane >> 5;                     // v-group
    const int vcol = chunk * 2 + vg;
    const int rbh = rule * 32 + bh;

    const float* __restrict__ pku  = kuA + ((size_t)bh * 256) * 128 + kl * 4;
    const float* __restrict__ pd   = dA  + ((size_t)rbh * 256) * 128 + kl * 4;
    const float* __restrict__ pq   = qc + (size_t)b * T_ * D_ + h * 128 + kl * 4;
    const float* __restrict__ pv   = vc + (size_t)b * T_ * D_ + h * 128 + vcol;
    const float* __restrict__ pbt  = (rule ? bs : bf) + (size_t)bh * 256;
    const float* __restrict__ pqkb = qkbA + (size_t)rbh * 256;
    float* __restrict__ obase = (rule ? o_slow : o_fast)
                                + (size_t)b * T_ * D_ + h * 128 + vcol;

    float S[4] = {0.f, 0.f, 0.f, 0.f};

#define DSTEP(TT, CUR, NXT) do {                                                   \
    float vp = 0.f, oq = 0.f;                                                      \
    _Pragma("unroll")                                                              \
    for (int j = 0; j < 4; ++j) {                                                  \
        vp = fmaf(CUR.ku[j] * CUR.d[j], S[j], vp);                                 \
        oq = fmaf(CUR.q[j]  * CUR.d[j], S[j], oq);                                 \
    }                                                                              \
    if ((TT) + 1 < T_) dload3(NXT, pku, pd, pq, pv, pbt, pqkb, (TT) + 1);          \
    vp += __shfl_xor(vp, 1);  oq += __shfl_xor(oq, 1);                             \
    vp += __shfl_xor(vp, 2);  oq += __shfl_xor(oq, 2);                             \
    vp += __shfl_xor(vp, 4);  oq += __shfl_xor(oq, 4);                             \
    vp += __shfl_xor(vp, 8);  oq += __shfl_xor(oq, 8);                             \
    vp += __shfl_xor(vp, 16); oq += __shfl_xor(oq, 16);                            \
    float dv = CUR.v - vp;                                                         \
    float o = fmaf(CUR.qkb, dv, oq);                                               \
    float btdv = CUR.bt * dv;                                                      \
    _Pragma("unroll")                                                              \
    for (int j = 0; j < 4; ++j)                                                    \
        S[j] = fmaf(CUR.d[j], S[j], CUR.ku[j] * btdv);                             \
    if (kl == 0) obase[(size_t)(TT) * D_] = o;                                     \
} while (0)

    DR3 r0, r1;
    dload3(r0, pku, pd, pq, pv, pbt, pqkb, 0);
    for (int t = 0; t < T_; t += 2) {
        DSTEP(t,     r0, r1);
        DSTEP(t + 1, r1, r0);
    }
#undef DSTEP
}

// ---------------- combine fast/slow + RMSNorm + sigmoid gate -> bf16 ----------------
__global__ __launch_bounds__(128) void combine_k(
    const float* __restrict__ of, const float* __restrict__ os,
    const float* __restrict__ lm, const float* __restrict__ graw,
    const float* __restrict__ g2b, const float* __restrict__ onw,
    ushort_t* __restrict__ ocb)
{
    int blk = blockIdx.x;          // (b*T+t)*H + h
    int h = blk & 15, bt = blk >> 4;
    int b = bt / T_, t = bt % T_;
    int v = threadIdx.x;
    size_t idx = (size_t)bt * D_ + h * 128 + v;
    float l = lm[((size_t)(b * H_ + h)) * T_ + t];
    float o = l * of[idx] + (1.f - l) * os[idx];
    float s = o * o;
    #pragma unroll
    for (int off = 32; off > 0; off >>= 1) s += __shfl_xor(s, off);
    __shared__ float ws2[2];
    if ((threadIdx.x & 63) == 0) ws2[threadIdx.x >> 6] = s;
    __syncthreads();
    float tot = ws2[0] + ws2[1];
    float rms = sqrtf(tot / 128.f + 1e-5f);
    float g = graw[idx] + g2b[h * 128 + v];
    ocb[idx] = f2bf(o / rms * onw[v] * sigmoidf_(g));
}

extern "C" void kernel_launch(void* const* d_in, const int* in_sizes, int n_in,
                              void* d_out, int out_size, void* d_ws, size_t ws_size,
                              hipStream_t stream)
{
    const float* x        = (const float*)d_in[0];
    const float* wq       = (const float*)d_in[1];
    const float* wk       = (const float*)d_in[2];
    const float* wv       = (const float*)d_in[3];
    const float* conv_q_w = (const float*)d_in[4];
    const float* conv_k_w = (const float*)d_in[5];
    const float* conv_v_w = (const float*)d_in[6];
    const float* A_log    = (const float*)d_in[7];
    const float* dt_bias  = (const float*)d_in[8];
    const float* proxy_w  = (const float*)d_in[9];
    const float* unc_w    = (const float*)d_in[10];
    const float* he       = (const float*)d_in[11];
    const float* mlp_w1   = (const float*)d_in[12];
    const float* mlp_b1   = (const float*)d_in[13];
    const float* mlp_w2   = (const float*)d_in[14];
    const float* mlp_b2   = (const float*)d_in[15];
    const float* bb_w     = (const float*)d_in[16];
    const float* bb_b     = (const float*)d_in[17];
    const float* bd_w     = (const float*)d_in[18];
    const float* bd_b     = (const float*)d_in[19];
    const float* lam_w    = (const float*)d_in[20];
    const float* lam_b    = (const float*)d_in[21];
    const float* ab_w     = (const float*)d_in[22];
    const float* ab_b     = (const float*)d_in[23];
    const float* ad_w     = (const float*)d_in[24];
    const float* ad_b     = (const float*)d_in[25];
    const float* g1_w     = (const float*)d_in[26];
    const float* g2_w     = (const float*)d_in[27];
    const float* g2_b     = (const float*)d_in[28];
    const float* onorm_w  = (const float*)d_in[29];
    const float* wo       = (const float*)d_in[30];
    float* out = (float*)d_out;

    float* ws = (float*)d_ws;
    const size_t SZ = (size_t)BT_ * D_;              // 1,048,576
    float* C_big = ws;                               // 512*6336 = 3,244,032
    float* qc    = C_big + (size_t)512 * 6336;
    float* kc    = qc + SZ;
    float* vc    = kc + SZ;
    float* graw  = vc + SZ;
    float* bf    = graw + SZ;                        // 6 x 8192 scalars
    float* bs    = bf + 8192;
    float* lm    = bs + 8192;
    float* af    = lm + 8192;
    float* as2   = af + 8192;
    float* kn    = as2 + 8192;
    float* gchan = kn + 8192;                        // 2048
    float* qkbA  = gchan + 2048;                     // 64*256 = 16,384
    float* kuA   = qkbA + 16384;                     // 32*256*128 = 1,048,576
    float* dA    = kuA + 1048576;                    // 64*256*128 = 2,097,152
    float* fend  = dA + 2097152;
    ushort_t* xb    = (ushort_t*)fend;               // 1,048,576 bf16
    ushort_t* gtmpb = xb + SZ;                       // 65,536 bf16
    // total ~= 45 MB

    float* o_fast  = C_big;                          // overlay (C_big dead after feats_k)
    float* o_slow  = C_big + SZ;
    ushort_t* ocb  = xb;                             // overlay (xb dead after gemm_proj)
    float* vhatA   = kuA;                            // overlay (kuA written after feats_k)
    ushort_t* kcb  = (ushort_t*)dA;                  // overlay (dA written after vhat GEMM)

    dim3 blk256(256);
    const float QSCALE = 0.08838834764831845f;       // DK^-0.5

    // 1. x -> bf16
    cvt_bf16<<<dim3(1024), blk256, 0, stream>>>(x, xb, (int)SZ);
    // 2. fused projections: [512][6336] = xb @ [wq|wk|wv|unc|g1]
    gemm_proj<<<dim3(99, 8), blk256, 0, stream>>>(xb, wq, wk, wv, unc_w, g1_w, C_big);
    // 3. gtmp cols -> bf16
    cvt_strided<<<dim3(64), blk256, 0, stream>>>(C_big, gtmpb);
    // 4. graw = gtmpb @ g2_w
    gemm_one<<<dim3(32, 8), blk256, 0, stream>>>(gtmpb, g2_w, graw, 2048, 128);
    // 5. conv + silu (q pre-scaled); kc also emitted as bf16
    conv_fused<<<dim3(24, BT_), blk256, 0, stream>>>(C_big, conv_q_w, conv_k_w, conv_v_w,
                                                     qc, kc, vc, kcb, QSCALE);
    // 6. vhat = kcb[8192,128] @ proxy[128,128]  (MFMA)
    gemm_one<<<dim3(2, 128), blk256, 0, stream>>>(kcb, proxy_w, vhatA, 128, 128);
    // 7. gchan precompute
    gchan_k<<<dim3(8), blk256, 0, stream>>>(A_log, dt_bias, gchan);
    // 8. per-(b,t,h) features + MLP (+entropy inline)
    feats_k<<<dim3(BT_ * H_), dim3(128), 0, stream>>>(
        kc, vc, vhatA, C_big, he, mlp_w1, mlp_b1, mlp_w2, mlp_b2,
        bb_w, bb_b, bd_w, bd_b, lam_w, lam_b, ab_w, ab_b, ad_w, ad_b,
        bf, bs, lm, af, as2, kn);
    // 9. precompute ku / d / qkb  (overwrites vhatA/kcb overlays — safe, both dead)
    precomp_k<<<dim3(256, 64), dim3(128), 0, stream>>>(
        kc, qc, kn, af, as2, bf, bs, gchan, kuA, dA, qkbA);
    // 10. delta-rule scan (fast+slow fused; XCD-swizzled; 4 waves/SIMD)
    delta_wave3<<<dim3(1024), blk256, 0, stream>>>(qc, vc, kuA, dA, qkbA, bf, bs,
                                                   o_fast, o_slow);
    // 11. combine + rmsnorm + gate -> bf16
    combine_k<<<dim3(BT_ * H_), dim3(128), 0, stream>>>(o_fast, o_slow, lm, graw,
                                                        g2_b, onorm_w, ocb);
    // 12. output projection
    gemm_one<<<dim3(32, 8), blk256, 0, stream>>>(ocb, wo, out, 2048, 2048);
}

// Round 6
// 302.314 us; speedup vs baseline: 4.4545x; 1.0156x over previous
//
#include <hip/hip_runtime.h>
#include <hip/hip_bf16.h>
#include <math.h>

#define H_ 16
#define DK_ 128
#define DV_ 128
#define D_ 2048
#define T_ 256
#define B_ 2
#define BT_ 512

typedef __attribute__((ext_vector_type(8))) short short8v;
typedef __attribute__((ext_vector_type(4))) float float4v;
typedef unsigned short ushort_t;

__device__ __forceinline__ float sigmoidf_(float x){ return 1.f/(1.f+expf(-x)); }
__device__ __forceinline__ float siluf_(float x){ return x/(1.f+expf(-x)); }
__device__ __forceinline__ ushort_t f2bf(float f){
    __hip_bfloat16 h = __float2bfloat16(f);
    return *reinterpret_cast<ushort_t*>(&h);
}
// swizzled LDS index (shorts) for 64-row x 32-col bf16 tiles; k multiple of 8 in use
__device__ __forceinline__ int swz(int row, int k){
    return row * 32 + ((((k >> 3) ^ (row & 3)) << 3) | (k & 7));
}

// ---------------- fp32 -> bf16 elementwise ----------------
__global__ void cvt_bf16(const float* __restrict__ in, ushort_t* __restrict__ out, int n){
    int i = (blockIdx.x * 256 + threadIdx.x) * 4;
    if (i >= n) return;
    float4 v = *(const float4*)&in[i];
    union { ushort_t s[4]; unsigned long long u; } p;
    p.s[0] = f2bf(v.x); p.s[1] = f2bf(v.y); p.s[2] = f2bf(v.z); p.s[3] = f2bf(v.w);
    *(unsigned long long*)&out[i] = p.u;
}

// ---------------- strided cvt: C_big cols [6208,6336) -> gtmpb [512][128] bf16 ------
__global__ void cvt_strided(const float* __restrict__ Cb, ushort_t* __restrict__ out){
    int i = (blockIdx.x * 256 + threadIdx.x) * 4;   // 65536 total
    int m = i >> 7, c = i & 127;
    float4 v = *(const float4*)&Cb[(size_t)m * 6336 + 6208 + c];
    union { ushort_t s[4]; unsigned long long u; } p;
    p.s[0] = f2bf(v.x); p.s[1] = f2bf(v.y); p.s[2] = f2bf(v.z); p.s[3] = f2bf(v.w);
    *(unsigned long long*)&out[i] = p.u;
}

// ---------------- GEMM core: C[64x64 tile] = A_bf16[M,K] @ W_f32[K,Nst] -------------
// W transpose-converted inline into swizzled LDS; register ping-pong prefetch.
__device__ __forceinline__ void gemm_core(
    const ushort_t* __restrict__ A, int K,
    const float* __restrict__ W, int Nst, int nloc0,
    float* __restrict__ C, int Cst, int m0, int n0out)
{
    __shared__ ushort_t Asub[2048];
    __shared__ ushort_t Bsub[2048];
    const int tid = threadIdx.x;
    const int wid = tid >> 6, lane = tid & 63;
    const int wr = (wid >> 1) * 32, wc = (wid & 1) * 32;
    const int lr = lane & 15, lk = (lane >> 4) * 8;
    const int rowA = tid >> 2, kqA = tid & 3;       // A staging: b128 per thread
    const int nW = tid & 63, kqW = tid >> 6;        // W staging: 8 scalar rows

    float4v acc[2][2];
    #pragma unroll
    for (int i = 0; i < 2; ++i)
        #pragma unroll
        for (int j = 0; j < 2; ++j) acc[i][j] = (float4v){0.f, 0.f, 0.f, 0.f};

    short8v aRa, aRb;
    float wRa[8], wRb[8];

#define LOADT(AR, WR, KOFF) do {                                                   \
    AR = *(const short8v*)&A[(size_t)(m0 + rowA) * K + (KOFF) + kqA * 8];          \
    _Pragma("unroll")                                                              \
    for (int r = 0; r < 8; ++r)                                                    \
        WR[r] = W[(size_t)((KOFF) + kqW * 8 + r) * Nst + nloc0 + nW];              \
} while (0)
#define STORET(AR, WR) do {                                                        \
    *(short8v*)&Asub[swz(rowA, kqA * 8)] = AR;                                     \
    union { ushort_t s[8]; short8v v; } pk;                                        \
    _Pragma("unroll")                                                              \
    for (int r = 0; r < 8; ++r) pk.s[r] = f2bf(WR[r]);                             \
    *(short8v*)&Bsub[swz(nW, kqW * 8)] = pk.v;                                     \
} while (0)
#define FRAGMMA() do {                                                             \
    short8v af0 = *(const short8v*)&Asub[swz(wr + lr, lk)];                        \
    short8v af1 = *(const short8v*)&Asub[swz(wr + 16 + lr, lk)];                   \
    short8v bf0 = *(const short8v*)&Bsub[swz(wc + lr, lk)];                        \
    short8v bf1 = *(const short8v*)&Bsub[swz(wc + 16 + lr, lk)];                   \
    acc[0][0] = __builtin_amdgcn_mfma_f32_16x16x32_bf16(af0, bf0, acc[0][0],0,0,0);\
    acc[0][1] = __builtin_amdgcn_mfma_f32_16x16x32_bf16(af0, bf1, acc[0][1],0,0,0);\
    acc[1][0] = __builtin_amdgcn_mfma_f32_16x16x32_bf16(af1, bf0, acc[1][0],0,0,0);\
    acc[1][1] = __builtin_amdgcn_mfma_f32_16x16x32_bf16(af1, bf1, acc[1][1],0,0,0);\
} while (0)

    LOADT(aRa, wRa, 0);
    for (int k0 = 0; k0 < K; k0 += 64) {
        STORET(aRa, wRa);
        __syncthreads();
        if (k0 + 32 < K) LOADT(aRb, wRb, k0 + 32);
        FRAGMMA();
        __syncthreads();
        STORET(aRb, wRb);
        __syncthreads();
        if (k0 + 64 < K) LOADT(aRa, wRa, k0 + 64);
        FRAGMMA();
        __syncthreads();
    }
#undef LOADT
#undef STORET
#undef FRAGMMA
    const int lq = (lane >> 4) * 4;
    #pragma unroll
    for (int mi = 0; mi < 2; ++mi)
        #pragma unroll
        for (int ni = 0; ni < 2; ++ni)
            #pragma unroll
            for (int j = 0; j < 4; ++j)
                C[(size_t)(m0 + wr + mi * 16 + lq + j) * Cst + (n0out + wc + ni * 16 + lr)]
                    = acc[mi][ni][j];
}

// fused projection GEMM: N = 6336 = wq(2048) | wk(2048) | wv(2048) | unc(64) | g1(128)
__global__ __launch_bounds__(256) void gemm_proj(const ushort_t* __restrict__ A,
    const float* __restrict__ wq, const float* __restrict__ wk, const float* __restrict__ wv,
    const float* __restrict__ unc, const float* __restrict__ g1, float* __restrict__ C)
{
    int n0 = blockIdx.x * 64, m0 = blockIdx.y * 64;
    const float* W; int nloc, Nst;
    if (n0 < 2048)      { W = wq;  nloc = n0;        Nst = 2048; }
    else if (n0 < 4096) { W = wk;  nloc = n0 - 2048; Nst = 2048; }
    else if (n0 < 6144) { W = wv;  nloc = n0 - 4096; Nst = 2048; }
    else if (n0 < 6208) { W = unc; nloc = n0 - 6144; Nst = 64; }
    else                { W = g1;  nloc = n0 - 6208; Nst = 128; }
    gemm_core(A, 2048, W, Nst, nloc, C, 6336, m0, n0);
}

// single-weight GEMM: C[M,N] = A[M,K] @ W[K,N]
__global__ __launch_bounds__(256) void gemm_one(const ushort_t* __restrict__ A,
    const float* __restrict__ W, float* __restrict__ C, int N, int K)
{
    gemm_core(A, K, W, N, blockIdx.x * 64, C, N, blockIdx.y * 64, blockIdx.x * 64);
}

// ---------------- fused causal depthwise conv (K=4) + SiLU over q|k|v --------------
// also emits bf16 copy of k-section (for the vhat GEMM)
__global__ void conv_fused(const float* __restrict__ Cb,
    const float* __restrict__ wq, const float* __restrict__ wk, const float* __restrict__ wv,
    float* __restrict__ qc, float* __restrict__ kc, float* __restrict__ vc,
    ushort_t* __restrict__ kcb, float qscale)
{
    int c  = blockIdx.x * 256 + threadIdx.x;   // 0..6143
    int bt = blockIdx.y;
    int b  = bt / T_, t = bt % T_;
    int which = c >> 11, cloc = c & 2047;
    const float* w = which == 0 ? wq : which == 1 ? wk : wv;
    float* o = which == 0 ? qc : which == 1 ? kc : vc;
    float scale = which == 0 ? qscale : 1.f;
    float acc = 0.f;
    #pragma unroll
    for (int j = 0; j < 4; ++j) {
        int tt = t - 3 + j;
        if (tt >= 0) acc = fmaf(w[cloc * 4 + j], Cb[((size_t)(b * T_ + tt)) * 6336 + c], acc);
    }
    float r = siluf_(acc) * scale;
    o[(size_t)bt * D_ + cloc] = r;
    if (which == 1) kcb[(size_t)bt * D_ + cloc] = f2bf(r);
}

// ---------------- g_chan (pre-scaled by log2(e) for exp2f) ----------------
__global__ void gchan_k(const float* __restrict__ A_log, const float* __restrict__ dt_bias,
                        float* __restrict__ gchan)
{
    int i = blockIdx.x * 256 + threadIdx.x;
    int h = i >> 7;
    float x = dt_bias[i];
    float sp = (x > 20.f) ? x : log1pf(expf(x));
    gchan[i] = -expf(A_log[h]) * sp * 1.44269504088896f;
}

// ---------------- per-(b,t,h) features (+inline entropy) + tiny MLP ----------------
__global__ __launch_bounds__(128) void feats_k(
    const float* __restrict__ kc, const float* __restrict__ vc,
    const float* __restrict__ vhatA, const float* __restrict__ Cb,
    const float* __restrict__ he,
    const float* __restrict__ w1, const float* __restrict__ b1,
    const float* __restrict__ w2, const float* __restrict__ b2,
    const float* __restrict__ bbw, const float* __restrict__ bbb,
    const float* __restrict__ bdw, const float* __restrict__ bdb,
    const float* __restrict__ lamw, const float* __restrict__ lamb,
    const float* __restrict__ abw, const float* __restrict__ abb,
    const float* __restrict__ adw, const float* __restrict__ adb,
    float* __restrict__ bf, float* __restrict__ bs, float* __restrict__ lm,
    float* __restrict__ af, float* __restrict__ as2, float* __restrict__ kn)
{
    int blk = blockIdx.x;          // (b*T+t)*H + h
    int h = blk & 15, bt = blk >> 4;
    int b = bt / T_, t = bt % T_;
    int v = threadIdx.x;           // 0..127
    __shared__ float part[2][5];
    __shared__ float tot5[5];
    __shared__ float feats8[8];
    __shared__ float hf1[32];
    __shared__ float hf[32];
    __shared__ float entSh;

    // entropy of softmax over 64 logits (wave 0)
    if (v < 64) {
        float x = Cb[(size_t)bt * 6336 + 6144 + v];
        float m = x;
        #pragma unroll
        for (int o = 32; o > 0; o >>= 1) m = fmaxf(m, __shfl_xor(m, o));
        float e = expf(x - m);
        float s = e;
        #pragma unroll
        for (int o = 32; o > 0; o >>= 1) s += __shfl_xor(s, o);
        float lp = (x - m) - logf(s);
        float c = -expf(lp) * lp;
        #pragma unroll
        for (int o = 32; o > 0; o >>= 1) c += __shfl_xor(c, o);
        if (v == 0) entSh = c / logf(64.f);
    }

    size_t base = (size_t)bt * D_ + h * 128;
    float kval = kc[base + v];
    float vval = vc[base + v];
    float vhat = vhatA[(size_t)blk * 128 + v];

    float e = vval - vhat;
    float sums[5] = {kval * kval, vval * vval, vhat * vhat, vval * vhat, e * e};
    #pragma unroll
    for (int i = 0; i < 5; ++i) {
        float s = sums[i];
        #pragma unroll
        for (int o = 32; o > 0; o >>= 1) s += __shfl_xor(s, o);
        if ((threadIdx.x & 63) == 0) part[threadIdx.x >> 6][i] = s;
    }
    __syncthreads();
    if (threadIdx.x < 5) tot5[threadIdx.x] = part[0][threadIdx.x] + part[1][threadIdx.x];
    __syncthreads();
    if (threadIdx.x == 0) {
        float k2 = tot5[0], v2 = tot5[1], vh2 = tot5[2], vvh = tot5[3], e2 = tot5[4];
        float knorm = sqrtf(k2);
        float err_n = sqrtf(e2);
        float v_n = sqrtf(v2);
        float vh_n = sqrtf(vh2);
        feats8[0] = entSh;
        feats8[1] = err_n / (v_n + 1e-6f);
        feats8[2] = vvh / (v_n * vh_n + 1e-6f);
        feats8[3] = log1pf(err_n);
        feats8[4] = he[h * 4 + 0];
        feats8[5] = he[h * 4 + 1];
        feats8[6] = he[h * 4 + 2];
        feats8[7] = he[h * 4 + 3];
        kn[((size_t)(b * H_ + h)) * T_ + t] = knorm;
    }
    __syncthreads();
    if (threadIdx.x < 32) {
        float a = b1[threadIdx.x];
        #pragma unroll
        for (int j = 0; j < 8; ++j) a = fmaf(feats8[j], w1[j * 32 + threadIdx.x], a);
        hf1[threadIdx.x] = siluf_(a);
    }
    __syncthreads();
    if (threadIdx.x < 32) {
        float a = b2[threadIdx.x];
        #pragma unroll
        for (int j = 0; j < 32; ++j) a = fmaf(hf1[j], w2[j * 32 + threadIdx.x], a);
        hf[threadIdx.x] = siluf_(a);
    }
    __syncthreads();
    if (threadIdx.x == 0) {
        float bb = bbb[0], bd = bdb[0], lv = lamb[0], ab = abb[0], ad = adb[0];
        #pragma unroll
        for (int j = 0; j < 32; ++j) {
            float hj = hf[j];
            bb = fmaf(hj, bbw[j], bb);
            bd = fmaf(hj, bdw[j], bd);
            lv = fmaf(hj, lamw[j], lv);
            ab = fmaf(hj, abw[j], ab);
            ad = fmaf(hj, adw[j], ad);
        }
        size_t o = ((size_t)(b * H_ + h)) * T_ + t;
        bf[o]  = sigmoidf_(bb + bd);
        bs[o]  = sigmoidf_(bb - bd);
        lm[o]  = sigmoidf_(lv);
        af[o]  = sigmoidf_(ab + ad);
        as2[o] = sigmoidf_(ab - ad);
    }
}

// ---------------- precompute scan operands: ku[bh][t][k]; scal4 {amp,beta,qkb} ----
__global__ __launch_bounds__(128) void precomp_k(
    const float* __restrict__ kc, const float* __restrict__ qc,
    const float* __restrict__ kn,
    const float* __restrict__ af, const float* __restrict__ as2,
    const float* __restrict__ bf, const float* __restrict__ bs,
    float* __restrict__ kuA, float4* __restrict__ scal4A)
{
    const int t = blockIdx.x;
    const int y = blockIdx.y;                // rule*32 + b*16 + h
    const int rule = y >> 5, b = (y >> 4) & 1, h = y & 15;
    const int k = threadIdx.x;
    const int sb = (b * 16 + h) * 256 + t;
    const float knv = kn[sb];
    const float am  = (rule ? as2 : af)[sb];
    const float btv = (rule ? bs : bf)[sb];
    const size_t idx = (size_t)(b * 256 + t) * D_ + h * 128 + k;
    const float kuv = kc[idx] / (knv + 1e-6f);
    if (rule == 0) kuA[((size_t)(b * 16 + h) * 256 + t) * 128 + k] = kuv;
    float p = qc[idx] * kuv;
    #pragma unroll
    for (int o = 32; o > 0; o >>= 1) p += __shfl_xor(p, o);
    __shared__ float pp[2];
    if ((k & 63) == 0) pp[k >> 6] = p;
    __syncthreads();
    if (k == 0) {
        float4 s; s.x = am; s.y = btv; s.z = (pp[0] + pp[1]) * btv; s.w = 0.f;
        scal4A[(size_t)y * 256 + t] = s;
    }
}

// ---------------- delta-rule scan v4: P-state, in-register decay, DPP-only ---------
// 1024 waves = 256 blocks x 4; block = one (bh,rule,sub); wave covers 8 v-cols.
// Wave = 16 k-lanes x 4 v-groups; lane owns P[8k][2v]. XCD-swizzled: bh>>2 per XCD.
struct DR4 { float ku[8], q[8], v0, v1; float4 sc; };

__device__ __forceinline__ void dload4(DR4& r,
    const float* __restrict__ pku, const float* __restrict__ pq,
    const float* __restrict__ pv, const float4* __restrict__ psc, int t)
{
    r.sc = psc[t];
    float4 a0 = *(const float4*)(pku + (size_t)t * 128);
    float4 a1 = *(const float4*)(pku + (size_t)t * 128 + 4);
    r.ku[0]=a0.x; r.ku[1]=a0.y; r.ku[2]=a0.z; r.ku[3]=a0.w;
    r.ku[4]=a1.x; r.ku[5]=a1.y; r.ku[6]=a1.z; r.ku[7]=a1.w;
    float4 b0 = *(const float4*)(pq + (size_t)t * D_);
    float4 b1 = *(const float4*)(pq + (size_t)t * D_ + 4);
    r.q[0]=b0.x; r.q[1]=b0.y; r.q[2]=b0.z; r.q[3]=b0.w;
    r.q[4]=b1.x; r.q[5]=b1.y; r.q[6]=b1.z; r.q[7]=b1.w;
    float2 vv = *(const float2*)(pv + (size_t)t * D_);
    r.v0 = vv.x; r.v1 = vv.y;
}

__global__ __launch_bounds__(256) void delta_wave4(
    const float* __restrict__ qc, const float* __restrict__ vc,
    const float* __restrict__ kuA, const float4* __restrict__ scal4A,
    const float* __restrict__ gchan,
    float* __restrict__ o_fast, float* __restrict__ o_slow)
{
    const int p  = blockIdx.x;                    // 0..255 ; XCD = p & 7
    const int lb = (p & 7) * 32 + (p >> 3);       // logical: bh*8 + rule*4 + sub
    const int bh   = lb >> 3;                     // 0..31 (4 bh per XCD)
    const int rule = (lb >> 2) & 1;
    const int sub  = lb & 3;
    const int wid  = threadIdx.x >> 6;
    const int lane = threadIdx.x & 63;
    const int kl = lane & 15, vg = lane >> 4;
    const int chunk = sub * 4 + wid;              // 0..15
    const int vcol  = chunk * 8 + vg * 2;         // owns vcol, vcol+1
    const int b = bh >> 4, h = bh & 15;
    const int rbh = rule * 32 + bh;

    const float*  __restrict__ pku = kuA + ((size_t)bh * 256) * 128 + kl * 8;
    const float*  __restrict__ pq  = qc + (size_t)b * T_ * D_ + h * 128 + kl * 8;
    const float*  __restrict__ pv  = vc + (size_t)b * T_ * D_ + h * 128 + vcol;
    const float4* __restrict__ psc = scal4A + (size_t)rbh * 256;
    float* __restrict__ obase = (rule ? o_slow : o_fast)
                                + (size_t)b * T_ * D_ + h * 128 + vcol;

    float gch[8];
    #pragma unroll
    for (int j = 0; j < 8; ++j) gch[j] = gchan[h * 128 + kl * 8 + j];

    float P[8][2];                               // decayed state P_t = D_t S_{t-1}
    #pragma unroll
    for (int j = 0; j < 8; ++j) { P[j][0] = 0.f; P[j][1] = 0.f; }

#define DSTEP(TT, CUR, NXT) do {                                                   \
    float vp0 = 0.f, vp1 = 0.f, oq0 = 0.f, oq1 = 0.f;                              \
    _Pragma("unroll")                                                              \
    for (int j = 0; j < 8; ++j) {                                                  \
        vp0 = fmaf(CUR.ku[j], P[j][0], vp0);                                       \
        vp1 = fmaf(CUR.ku[j], P[j][1], vp1);                                       \
        oq0 = fmaf(CUR.q[j],  P[j][0], oq0);                                       \
        oq1 = fmaf(CUR.q[j],  P[j][1], oq1);                                       \
    }                                                                              \
    if ((TT) + 1 < T_) dload4(NXT, pku, pq, pv, psc, (TT) + 1);                    \
    vp0 += __shfl_xor(vp0, 1); vp1 += __shfl_xor(vp1, 1);                          \
    oq0 += __shfl_xor(oq0, 1); oq1 += __shfl_xor(oq1, 1);                          \
    vp0 += __shfl_xor(vp0, 2); vp1 += __shfl_xor(vp1, 2);                          \
    oq0 += __shfl_xor(oq0, 2); oq1 += __shfl_xor(oq1, 2);                          \
    vp0 += __shfl_xor(vp0, 4); vp1 += __shfl_xor(vp1, 4);                          \
    oq0 += __shfl_xor(oq0, 4); oq1 += __shfl_xor(oq1, 4);                          \
    vp0 += __shfl_xor(vp0, 8); vp1 += __shfl_xor(vp1, 8);                          \
    oq0 += __shfl_xor(oq0, 8); oq1 += __shfl_xor(oq1, 8);                          \
    float dv0 = CUR.v0 - vp0, dv1 = CUR.v1 - vp1;                                  \
    float o0 = fmaf(CUR.sc.z, dv0, oq0);                                           \
    float o1 = fmaf(CUR.sc.z, dv1, oq1);                                           \
    float bd0 = CUR.sc.y * dv0, bd1 = CUR.sc.y * dv1;                              \
    float amn = NXT.sc.x;                                                          \
    _Pragma("unroll")                                                              \
    for (int j = 0; j < 8; ++j) {                                                  \
        float dn = exp2f(gch[j] * amn);                                            \
        P[j][0] = dn * fmaf(CUR.ku[j], bd0, P[j][0]);                              \
        P[j][1] = dn * fmaf(CUR.ku[j], bd1, P[j][1]);                              \
    }                                                                              \
    if (kl == 0) { float2 ov; ov.x = o0; ov.y = o1;                                \
                   *(float2*)&obase[(size_t)(TT) * D_] = ov; }                     \
} while (0)

    DR4 r0, r1;
    dload4(r0, pku, pq, pv, psc, 0);
    r1 = r0;   // so first step's "next amp" init is defined before prefetch lands
    for (int t = 0; t < T_; t += 2) {
        DSTEP(t,     r0, r1);
        DSTEP(t + 1, r1, r0);
    }
#undef DSTEP
}

// ---------------- combine fast/slow + RMSNorm + sigmoid gate -> bf16 ----------------
__global__ __launch_bounds__(128) void combine_k(
    const float* __restrict__ of, const float* __restrict__ os,
    const float* __restrict__ lm, const float* __restrict__ graw,
    const float* __restrict__ g2b, const float* __restrict__ onw,
    ushort_t* __restrict__ ocb)
{
    int blk = blockIdx.x;          // (b*T+t)*H + h
    int h = blk & 15, bt = blk >> 4;
    int b = bt / T_, t = bt % T_;
    int v = threadIdx.x;
    size_t idx = (size_t)bt * D_ + h * 128 + v;
    float l = lm[((size_t)(b * H_ + h)) * T_ + t];
    float o = l * of[idx] + (1.f - l) * os[idx];
    float s = o * o;
    #pragma unroll
    for (int off = 32; off > 0; off >>= 1) s += __shfl_xor(s, off);
    __shared__ float ws2[2];
    if ((threadIdx.x & 63) == 0) ws2[threadIdx.x >> 6] = s;
    __syncthreads();
    float tot = ws2[0] + ws2[1];
    float rms = sqrtf(tot / 128.f + 1e-5f);
    float g = graw[idx] + g2b[h * 128 + v];
    ocb[idx] = f2bf(o / rms * onw[v] * sigmoidf_(g));
}

extern "C" void kernel_launch(void* const* d_in, const int* in_sizes, int n_in,
                              void* d_out, int out_size, void* d_ws, size_t ws_size,
                              hipStream_t stream)
{
    const float* x        = (const float*)d_in[0];
    const float* wq       = (const float*)d_in[1];
    const float* wk       = (const float*)d_in[2];
    const float* wv       = (const float*)d_in[3];
    const float* conv_q_w = (const float*)d_in[4];
    const float* conv_k_w = (const float*)d_in[5];
    const float* conv_v_w = (const float*)d_in[6];
    const float* A_log    = (const float*)d_in[7];
    const float* dt_bias  = (const float*)d_in[8];
    const float* proxy_w  = (const float*)d_in[9];
    const float* unc_w    = (const float*)d_in[10];
    const float* he       = (const float*)d_in[11];
    const float* mlp_w1   = (const float*)d_in[12];
    const float* mlp_b1   = (const float*)d_in[13];
    const float* mlp_w2   = (const float*)d_in[14];
    const float* mlp_b2   = (const float*)d_in[15];
    const float* bb_w     = (const float*)d_in[16];
    const float* bb_b     = (const float*)d_in[17];
    const float* bd_w     = (const float*)d_in[18];
    const float* bd_b     = (const float*)d_in[19];
    const float* lam_w    = (const float*)d_in[20];
    const float* lam_b    = (const float*)d_in[21];
    const float* ab_w     = (const float*)d_in[22];
    const float* ab_b     = (const float*)d_in[23];
    const float* ad_w     = (const float*)d_in[24];
    const float* ad_b     = (const float*)d_in[25];
    const float* g1_w     = (const float*)d_in[26];
    const float* g2_w     = (const float*)d_in[27];
    const float* g2_b     = (const float*)d_in[28];
    const float* onorm_w  = (const float*)d_in[29];
    const float* wo       = (const float*)d_in[30];
    float* out = (float*)d_out;

    float* ws = (float*)d_ws;
    const size_t SZ = (size_t)BT_ * D_;              // 1,048,576
    float* C_big = ws;                               // 512*6336 = 3,244,032
    float* qc    = C_big + (size_t)512 * 6336;
    float* kc    = qc + SZ;
    float* vc    = kc + SZ;
    float* graw  = vc + SZ;
    float* bf    = graw + SZ;                        // 6 x 8192 scalars
    float* bs    = bf + 8192;
    float* lm    = bs + 8192;
    float* af    = lm + 8192;
    float* as2   = af + 8192;
    float* kn    = as2 + 8192;
    float* gchan = kn + 8192;                        // 2048
    float* scal4 = gchan + 2048;                     // 64*256*4 = 65,536
    float* kuA   = scal4 + 65536;                    // 32*256*128 = 1,048,576
    float* scr2  = kuA + 1048576;                    // 524,288 floats (kcb bf16)
    float* fend  = scr2 + 524288;
    ushort_t* xb    = (ushort_t*)fend;               // 1,048,576 bf16
    ushort_t* gtmpb = xb + SZ;                       // 65,536 bf16
    // total ~= 37 MB

    float* o_fast  = C_big;                          // overlay (C_big dead after feats_k)
    float* o_slow  = C_big + SZ;
    ushort_t* ocb  = xb;                             // overlay (xb dead after gemm_proj)
    float* vhatA   = kuA;                            // overlay (kuA written in precomp, after feats_k)
    ushort_t* kcb  = (ushort_t*)scr2;

    dim3 blk256(256);
    const float QSCALE = 0.08838834764831845f;       // DK^-0.5

    // 1. x -> bf16
    cvt_bf16<<<dim3(1024), blk256, 0, stream>>>(x, xb, (int)SZ);
    // 2. fused projections: [512][6336] = xb @ [wq|wk|wv|unc|g1]
    gemm_proj<<<dim3(99, 8), blk256, 0, stream>>>(xb, wq, wk, wv, unc_w, g1_w, C_big);
    // 3. gtmp cols -> bf16
    cvt_strided<<<dim3(64), blk256, 0, stream>>>(C_big, gtmpb);
    // 4. graw = gtmpb @ g2_w
    gemm_one<<<dim3(32, 8), blk256, 0, stream>>>(gtmpb, g2_w, graw, 2048, 128);
    // 5. conv + silu (q pre-scaled); kc also emitted as bf16
    conv_fused<<<dim3(24, BT_), blk256, 0, stream>>>(C_big, conv_q_w, conv_k_w, conv_v_w,
                                                     qc, kc, vc, kcb, QSCALE);
    // 6. vhat = kcb[8192,128] @ proxy[128,128]  (MFMA)
    gemm_one<<<dim3(2, 128), blk256, 0, stream>>>(kcb, proxy_w, vhatA, 128, 128);
    // 7. gchan precompute
    gchan_k<<<dim3(8), blk256, 0, stream>>>(A_log, dt_bias, gchan);
    // 8. per-(b,t,h) features + MLP (+entropy inline)
    feats_k<<<dim3(BT_ * H_), dim3(128), 0, stream>>>(
        kc, vc, vhatA, C_big, he, mlp_w1, mlp_b1, mlp_w2, mlp_b2,
        bb_w, bb_b, bd_w, bd_b, lam_w, lam_b, ab_w, ab_b, ad_w, ad_b,
        bf, bs, lm, af, as2, kn);
    // 9. precompute ku + packed per-step scalars (overwrites vhatA overlay — safe)
    precomp_k<<<dim3(256, 64), dim3(128), 0, stream>>>(
        kc, qc, kn, af, as2, bf, bs, kuA, (float4*)scal4);
    // 10. delta-rule scan (1024 waves, 1/SIMD, XCD-swizzled, DPP-only reductions)
    delta_wave4<<<dim3(256), blk256, 0, stream>>>(qc, vc, kuA, (const float4*)scal4,
                                                  gchan, o_fast, o_slow);
    // 11. combine + rmsnorm + gate -> bf16
    combine_k<<<dim3(BT_ * H_), dim3(128), 0, stream>>>(o_fast, o_slow, lm, graw,
                                                        g2_b, onorm_w, ocb);
    // 12. output projection
    gemm_one<<<dim3(32, 8), blk256, 0, stream>>>(ocb, wo, out, 2048, 2048);
}